// Round 8
// baseline (234.718 us; speedup 1.0000x reference)
//
#include <hip/hip_runtime.h>

#define DF 128
#define AST 136   // padded LDS row stride (bf16 elems)
#define EPB 2048  // edges per block in bucket passes

typedef float f32x4 __attribute__((ext_vector_type(4)));
typedef short bf16x8 __attribute__((ext_vector_type(8)));

__device__ __forceinline__ ushort f2bf(float f) {
  union { float f; uint u; } c; c.f = f;
  uint u = c.u;
  uint r = (u + 0x7fffu + ((u >> 16) & 1u)) >> 16;   // RNE
  return (ushort)r;
}
__device__ __forceinline__ float bf_lo(uint v) { union { uint u; float f; } c; c.u = v << 16; return c.f; }
__device__ __forceinline__ float bf_hi(uint v) { union { uint u; float f; } c; c.u = v & 0xffff0000u; return c.f; }

__device__ __forceinline__ void addv8(float* acc, uint4 v) {
  acc[0] += bf_lo(v.x); acc[1] += bf_hi(v.x);
  acc[2] += bf_lo(v.y); acc[3] += bf_hi(v.y);
  acc[4] += bf_lo(v.z); acc[5] += bf_hi(v.z);
  acc[6] += bf_lo(v.w); acc[7] += bf_hi(v.w);
}

// ---------------- prep: convert x->bf16, transpose W1/W2/W3, zero dummy rows ----------------
__global__ void prep_kernel(const float* __restrict__ x, ushort* __restrict__ xb,
                            const float* __restrict__ W1, ushort* __restrict__ Wt1,
                            const float* __restrict__ W2, ushort* __restrict__ Wt2,
                            const float* __restrict__ W3, ushort* __restrict__ W3t,
                            ushort* __restrict__ xbN, ushort* __restrict__ bufBN, int n4) {
  int i = blockIdx.x * 256 + threadIdx.x;
  if (i < n4) {
    float4 v = ((const float4*)x)[i];
    ushort4 o; o.x = f2bf(v.x); o.y = f2bf(v.y); o.z = f2bf(v.z); o.w = f2bf(v.w);
    ((ushort4*)xb)[i] = o;
    return;
  }
  int j = i - n4;
  if (j < DF * DF) {
    int nr = j >> 7, k = j & 127;
    Wt1[j] = f2bf(W1[(size_t)k * DF + nr]);
    return;
  }
  j -= DF * DF;
  if (j < DF * DF) {
    int nr = j >> 7, k = j & 127;
    Wt2[j] = f2bf(W2[(size_t)k * DF + nr]);
    return;
  }
  j -= DF * DF;
  if (j < 16 * DF) {
    int nr = j >> 7, k = j & 127;
    W3t[j] = (nr < 10) ? f2bf(W3[(size_t)k * 10 + nr]) : (ushort)0;
    return;
  }
  j -= 16 * DF;
  if (j < 16) { ((uint4*)xbN)[j] = (uint4){0, 0, 0, 0}; return; }
  j -= 16;
  if (j < 16) { ((uint4*)bufBN)[j] = (uint4){0, 0, 0, 0}; }
}

// ---------------- CSR build: two-level counting sort (bucket = dst >> 8) ----------------

__global__ void bucket_hist_kernel(const int* __restrict__ dst, int* __restrict__ histG,
                                   int E, int nbuck, int nblocks) {
  extern __shared__ int lh[];
  int tid = threadIdx.x, blk = blockIdx.x;
  for (int i = tid; i < nbuck; i += 256) lh[i] = 0;
  __syncthreads();
  int base = blk * EPB;
#pragma unroll
  for (int it = 0; it < EPB / 256; ++it) {
    int e = base + it * 256 + tid;
    if (e < E) atomicAdd(&lh[dst[e] >> 8], 1);
  }
  __syncthreads();
  for (int i = tid; i < nbuck; i += 256) histG[(size_t)i * nblocks + blk] = lh[i];
}

__global__ void scan1_kernel(const int* __restrict__ cnt, int* __restrict__ excl,
                             int* __restrict__ bsums, int n) {
  __shared__ int wsum[4];
  int t = threadIdx.x;
  int base = blockIdx.x * 1024 + t * 4;
  int v[4]; int s = 0;
#pragma unroll
  for (int i = 0; i < 4; i++) { int d = (base + i < n) ? cnt[base + i] : 0; v[i] = s; s += d; }
  int lane = t & 63, w = t >> 6;
  int sc = s;
#pragma unroll
  for (int off = 1; off < 64; off <<= 1) { int o = __shfl_up(sc, off); if (lane >= off) sc += o; }
  if (lane == 63) wsum[w] = sc;
  __syncthreads();
  int woff = 0;
  for (int i = 0; i < w; i++) woff += wsum[i];
  int toff = woff + (sc - s);
#pragma unroll
  for (int i = 0; i < 4; i++) if (base + i < n) excl[base + i] = toff + v[i];
  if (t == 255) bsums[blockIdx.x] = woff + sc;
}

__global__ void scan2_kernel(int* bsums, int nb) {
  __shared__ int wsum[16];
  int t = threadIdx.x;
  int v = (t < nb) ? bsums[t] : 0;
  int lane = t & 63, w = t >> 6;
  int sc = v;
#pragma unroll
  for (int off = 1; off < 64; off <<= 1) { int o = __shfl_up(sc, off); if (lane >= off) sc += o; }
  if (lane == 63) wsum[w] = sc;
  __syncthreads();
  int woff = 0;
  for (int i = 0; i < w; i++) woff += wsum[i];
  if (t < nb) bsums[t] = woff + sc - v;
}

__global__ void bucket_scatter_kernel(const int* __restrict__ src, const int* __restrict__ dst,
                                      const int* __restrict__ histE, const int* __restrict__ bsums,
                                      uint* __restrict__ eb, int E, int nbuck, int nblocks) {
  extern __shared__ int lc[];
  int tid = threadIdx.x, blk = blockIdx.x;
  for (int i = tid; i < nbuck; i += 256) {
    int idx = i * nblocks + blk;
    lc[i] = histE[idx] + bsums[idx >> 10];
  }
  __syncthreads();
  int base = blk * EPB;
#pragma unroll
  for (int it = 0; it < EPB / 256; ++it) {
    int e = base + it * 256 + tid;
    if (e < E) {
      int d = dst[e];
      int pos = atomicAdd(&lc[d >> 8], 1);
      eb[pos] = (uint)src[e] | ((uint)(d & 255) << 24);
    }
  }
}

__global__ void bucket_sort_kernel(const uint* __restrict__ eb,
                                   const int* __restrict__ histE, const int* __restrict__ bsums,
                                   int* __restrict__ rowptr, int* __restrict__ csr,
                                   int N, int E, int nbuck, int nblocks) {
  __shared__ int cnt[256];
  __shared__ int cursor[256];
  __shared__ int wsum[4];
  int tid = threadIdx.x, b = blockIdx.x;
  int idx = b * nblocks;
  int beg = histE[idx] + bsums[idx >> 10];
  int end = E;
  if (b + 1 < nbuck) { int i2 = (b + 1) * nblocks; end = histE[i2] + bsums[i2 >> 10]; }
  cnt[tid] = 0;
  __syncthreads();
  for (int e = beg + tid; e < end; e += 256)
    atomicAdd(&cnt[eb[e] >> 24], 1);
  __syncthreads();
  int v = cnt[tid];
  int lane = tid & 63, w = tid >> 6;
  int sc = v;
#pragma unroll
  for (int off = 1; off < 64; off <<= 1) { int o = __shfl_up(sc, off); if (lane >= off) sc += o; }
  if (lane == 63) wsum[w] = sc;
  __syncthreads();
  int woff = 0;
  for (int i = 0; i < w; i++) woff += wsum[i];
  int excl = woff + sc - v;
  int node = (b << 8) + tid;
  if (node <= N) rowptr[node] = beg + excl;
  cursor[tid] = beg + excl;
  __syncthreads();
  for (int e = beg + tid; e < end; e += 256) {
    uint vv = eb[e];
    int pos = atomicAdd(&cursor[vv >> 24], 1);
    csr[pos] = (int)(vv & 0x00FFFFFFu);
  }
}

// ---------------- scatter-mean: one 16-lane group per node (4 nodes/wave) ----------------
// Each group loads 4 full 256B rows per iteration (16 rows in flight per wave),
// accumulates its node's row directly (no cross-lane reduce). OOR edges clamp
// to all-zero row n (cache-resident). 4-edge granularity -> ~9% slot waste.
__global__ __launch_bounds__(256) void aggregate_kernel(
    const ushort* __restrict__ xb, const int* __restrict__ rowptr,
    const int* __restrict__ csr, ushort* __restrict__ out, int n) {
  int tid = threadIdx.x;
  int node = (blockIdx.x * 256 + tid) >> 4;
  if (node >= n) return;
  uint c16 = (uint)(tid & 15) * 16u;      // byte offset within 256B row
  int beg = rowptr[node], end = rowptr[node + 1];
  const char* xbase = (const char*)xb;
  float acc[8];
#pragma unroll
  for (int i = 0; i < 8; i++) acc[i] = 0.f;

#pragma unroll 1
  for (int e = beg; e < end; e += 4) {
    int last = end - 1;
    int e1 = e + 1, e2 = e + 2, e3 = e + 3;
    uint r0 = (uint)csr[e];
    uint r1 = (e1 < end) ? (uint)csr[e1] : (uint)n;
    uint r2 = (e2 < end) ? (uint)csr[e2] : (uint)n;
    uint r3 = (e3 < end) ? (uint)csr[e3] : (uint)n;
    uint4 v0 = *(const uint4*)(xbase + (r0 * 256u + c16));
    uint4 v1 = *(const uint4*)(xbase + (r1 * 256u + c16));
    uint4 v2 = *(const uint4*)(xbase + (r2 * 256u + c16));
    uint4 v3 = *(const uint4*)(xbase + (r3 * 256u + c16));
    addv8(acc, v0);
    addv8(acc, v1);
    addv8(acc, v2);
    addv8(acc, v3);
  }

  int deg = end - beg;
  uint4 r;
  if (deg > 0) {
    float inv = 1.0f / (float)deg;
    r.x = (uint)f2bf(acc[0] * inv) | ((uint)f2bf(acc[1] * inv) << 16);
    r.y = (uint)f2bf(acc[2] * inv) | ((uint)f2bf(acc[3] * inv) << 16);
    r.z = (uint)f2bf(acc[4] * inv) | ((uint)f2bf(acc[5] * inv) << 16);
    r.w = (uint)f2bf(acc[6] * inv) | ((uint)f2bf(acc[7] * inv) << 16);
  } else {
    r = *(const uint4*)(xbase + ((uint)node * 256u + c16));
  }
  *(uint4*)((char*)out + ((uint)node * 256u + c16)) = r;
}

// ---------------- GEMM1 [n x 128] @ W[128 x 128] + bias + tanh, bf16 MFMA ----------------
// A staged in LDS (coalesced); B-fragments read directly from global (W is
// 32KB, L1/L2-resident across all blocks). LDS 17KB -> 8 blocks/CU.
__global__ __launch_bounds__(256) void gemm_tanh_mfma(
    const ushort* __restrict__ A, const ushort* __restrict__ Wt,
    const float* __restrict__ bias, ushort* __restrict__ out, int n) {
  __shared__ ushort As[64 * AST];
  int tid = threadIdx.x;
  int node0 = blockIdx.x * 64;

  for (int i = tid; i < 64 * 16; i += 256) {
    int r = i >> 4, c = i & 15;
    int node = node0 + r; if (node >= n) node = n - 1;
    uint4 v = ((const uint4*)(A + (size_t)node * DF))[c];
    *(uint4*)&As[r * AST + c * 8] = v;
  }
  __syncthreads();

  int lane = tid & 63, w = tid >> 6;
  int wr = (w >> 1) * 32;
  int wc = (w & 1) * 64;
  int r16 = lane & 15, g8 = (lane >> 4) * 8;

  f32x4 acc[2][4];
#pragma unroll
  for (int i = 0; i < 2; i++)
#pragma unroll
    for (int j = 0; j < 4; j++) acc[i][j] = (f32x4){0.f, 0.f, 0.f, 0.f};

#pragma unroll
  for (int ks = 0; ks < 4; ++ks) {
    int k0 = ks * 32 + g8;
    bf16x8 a0 = *(const bf16x8*)&As[(wr + r16) * AST + k0];
    bf16x8 a1 = *(const bf16x8*)&As[(wr + 16 + r16) * AST + k0];
#pragma unroll
    for (int j = 0; j < 4; j++) {
      bf16x8 b = *(const bf16x8*)&Wt[(wc + j * 16 + r16) * DF + k0];
      acc[0][j] = __builtin_amdgcn_mfma_f32_16x16x32_bf16(a0, b, acc[0][j], 0, 0, 0);
      acc[1][j] = __builtin_amdgcn_mfma_f32_16x16x32_bf16(a1, b, acc[1][j], 0, 0, 0);
    }
  }

#pragma unroll
  for (int mi = 0; mi < 2; mi++) {
#pragma unroll
    for (int j = 0; j < 4; j++) {
      int col = wc + j * 16 + r16;
      float bv = bias[col];
      int rowb = wr + mi * 16 + (lane >> 4) * 4;
#pragma unroll
      for (int q = 0; q < 4; q++) {
        int node = node0 + rowb + q;
        if (node < n) {
          float vv = tanhf(acc[mi][j][q] + bv);
          out[(size_t)node * DF + col] = f2bf(vv);
        }
      }
    }
  }
}

// ---------------- GEMM2 + head fused: h2 = tanh(A@W2+b2) -> LDS -> logits = h2@W3+b3
__global__ __launch_bounds__(256) void gemm2_head_mfma(
    const ushort* __restrict__ A, const ushort* __restrict__ Wt,
    const float* __restrict__ bias, const ushort* __restrict__ W3t,
    const float* __restrict__ b3, float* __restrict__ out, int n) {
  __shared__ ushort As[64 * AST];
  int tid = threadIdx.x;
  int node0 = blockIdx.x * 64;

  for (int i = tid; i < 64 * 16; i += 256) {
    int r = i >> 4, c = i & 15;
    int node = node0 + r; if (node >= n) node = n - 1;
    uint4 v = ((const uint4*)(A + (size_t)node * DF))[c];
    *(uint4*)&As[r * AST + c * 8] = v;
  }
  __syncthreads();

  int lane = tid & 63, w = tid >> 6;
  int wr = (w >> 1) * 32, wc = (w & 1) * 64;
  int r16 = lane & 15, g8 = (lane >> 4) * 8;

  f32x4 acc[2][4];
#pragma unroll
  for (int i = 0; i < 2; i++)
#pragma unroll
    for (int j = 0; j < 4; j++) acc[i][j] = (f32x4){0.f, 0.f, 0.f, 0.f};

#pragma unroll
  for (int ks = 0; ks < 4; ++ks) {
    int k0 = ks * 32 + g8;
    bf16x8 a0 = *(const bf16x8*)&As[(wr + r16) * AST + k0];
    bf16x8 a1 = *(const bf16x8*)&As[(wr + 16 + r16) * AST + k0];
#pragma unroll
    for (int j = 0; j < 4; ++j) {
      bf16x8 b = *(const bf16x8*)&Wt[(wc + j * 16 + r16) * DF + k0];
      acc[0][j] = __builtin_amdgcn_mfma_f32_16x16x32_bf16(a0, b, acc[0][j], 0, 0, 0);
      acc[1][j] = __builtin_amdgcn_mfma_f32_16x16x32_bf16(a1, b, acc[1][j], 0, 0, 0);
    }
  }

  __syncthreads();   // all As reads done; overwrite with h2
#pragma unroll
  for (int mi = 0; mi < 2; mi++) {
#pragma unroll
    for (int j = 0; j < 4; j++) {
      int col = wc + j * 16 + r16;
      float bv = bias[col];
      int rowb = wr + mi * 16 + (lane >> 4) * 4;
#pragma unroll
      for (int q = 0; q < 4; q++)
        As[(rowb + q) * AST + col] = f2bf(tanhf(acc[mi][j][q] + bv));
    }
  }
  __syncthreads();

  // head: wave w handles rows [w*16, w*16+16)
  f32x4 h = (f32x4){0.f, 0.f, 0.f, 0.f};
#pragma unroll
  for (int ks = 0; ks < 4; ++ks) {
    int k0 = ks * 32 + g8;
    bf16x8 a = *(const bf16x8*)&As[(w * 16 + r16) * AST + k0];
    bf16x8 b = *(const bf16x8*)&W3t[r16 * DF + k0];
    h = __builtin_amdgcn_mfma_f32_16x16x32_bf16(a, b, h, 0, 0, 0);
  }
  if (r16 < 10) {
    float bv = b3[r16];
    int rowb = w * 16 + (lane >> 4) * 4;
#pragma unroll
    for (int q = 0; q < 4; q++) {
      int node = node0 + rowb + q;
      if (node < n) out[(size_t)node * 10 + r16] = h[q] + bv;
    }
  }
}

extern "C" void kernel_launch(void* const* d_in, const int* in_sizes, int n_in,
                              void* d_out, int out_size, void* d_ws, size_t ws_size,
                              hipStream_t stream) {
  const float* x    = (const float*)d_in[0];
  const int*   esrc = (const int*)d_in[1];
  const int*   edst = (const int*)d_in[2];
  const float* W1   = (const float*)d_in[3];
  const float* b1   = (const float*)d_in[4];
  const float* W2   = (const float*)d_in[5];
  const float* b2   = (const float*)d_in[6];
  const float* W3   = (const float*)d_in[7];
  const float* b3   = (const float*)d_in[8];
  float* out = (float*)d_out;

  const int N = in_sizes[0] / DF;   // 100000
  const int E = in_sizes[1];        // 1600000

  const int nbuck   = (N + 255) >> 8;            // 391
  const int nblocks = (E + EPB - 1) / EPB;       // 782
  const int M = nbuck * nblocks;                 // ~306K

  // workspace layout
  char* ws = (char*)d_ws;
  int*  rowptr = (int*)ws;               // N+1
  int*  csr    = rowptr + (N + 1);       // E
  int*  histG  = csr + E;                // M
  int*  histE  = histG + M;              // M
  int*  bsums2 = histE + M;              // 1024
  uint* eb     = (uint*)(bsums2 + 1024); // E
  size_t off = (size_t)((char*)(eb + E) - ws);
  off = (off + 255) & ~(size_t)255;
  ushort* xb  = (ushort*)(ws + off);     off += (size_t)(N + 1) * DF * 2; off = (off + 255) & ~(size_t)255;
  ushort* Wt1 = (ushort*)(ws + off);     off += (size_t)DF * DF * 2;
  ushort* Wt2 = (ushort*)(ws + off);     off += (size_t)DF * DF * 2;
  ushort* W3t = (ushort*)(ws + off);     off += (size_t)16 * DF * 2; off = (off + 255) & ~(size_t)255;
  ushort* bufA = (ushort*)(ws + off);    off += (size_t)N * DF * 2; off = (off + 255) & ~(size_t)255;
  ushort* bufB = (ushort*)(ws + off);    // N+1 rows (zero row N)

  // prep (convert + 3 transposes + zero dummy rows in one launch)
  int n4 = N * DF / 4;
  int prep_total = n4 + 2 * DF * DF + 16 * DF + 32;
  prep_kernel<<<(prep_total + 255) / 256, 256, 0, stream>>>(
      x, xb, W1, Wt1, W2, Wt2, W3, W3t, xb + (size_t)N * DF, bufB + (size_t)N * DF, n4);

  // CSR build
  size_t lds_b = (size_t)nbuck * sizeof(int);
  bucket_hist_kernel<<<nblocks, 256, lds_b, stream>>>(edst, histG, E, nbuck, nblocks);
  int nb_m = (M + 1023) / 1024;
  scan1_kernel<<<nb_m, 256, 0, stream>>>(histG, histE, bsums2, M);
  scan2_kernel<<<1, 1024, 0, stream>>>(bsums2, nb_m);
  bucket_scatter_kernel<<<nblocks, 256, lds_b, stream>>>(esrc, edst, histE, bsums2, eb, E, nbuck, nblocks);
  bucket_sort_kernel<<<nbuck, 256, 0, stream>>>(eb, histE, bsums2, rowptr, csr, N, E, nbuck, nblocks);

  int agg_blocks = (N + 15) / 16;          // one 16-lane group per node
  int gemm_blocks = (N + 63) / 64;

  // layer 1
  aggregate_kernel<<<agg_blocks, 256, 0, stream>>>(xb, rowptr, csr, bufA, N);
  gemm_tanh_mfma<<<gemm_blocks, 256, 0, stream>>>(bufA, Wt1, b1, bufB, N);
  // layer 2 + head
  aggregate_kernel<<<agg_blocks, 256, 0, stream>>>(bufB, rowptr, csr, bufA, N);
  gemm2_head_mfma<<<gemm_blocks, 256, 0, stream>>>(bufA, Wt2, b2, W3t, b3, out, N);
}

// Round 9
// 221.922 us; speedup vs baseline: 1.0577x; 1.0577x over previous
//
#include <hip/hip_runtime.h>

#define DF 128
#define AST 136   // padded LDS row stride (bf16 elems)
#define EPB 2048  // edges per block in bucket passes

typedef float f32x4 __attribute__((ext_vector_type(4)));
typedef short bf16x8 __attribute__((ext_vector_type(8)));

__device__ __forceinline__ ushort f2bf(float f) {
  union { float f; uint u; } c; c.f = f;
  uint u = c.u;
  uint r = (u + 0x7fffu + ((u >> 16) & 1u)) >> 16;   // RNE
  return (ushort)r;
}
__device__ __forceinline__ float bf_lo(uint v) { union { uint u; float f; } c; c.u = v << 16; return c.f; }
__device__ __forceinline__ float bf_hi(uint v) { union { uint u; float f; } c; c.u = v & 0xffff0000u; return c.f; }

__device__ __forceinline__ void addv8(float* acc, uint4 v) {
  acc[0] += bf_lo(v.x); acc[1] += bf_hi(v.x);
  acc[2] += bf_lo(v.y); acc[3] += bf_hi(v.y);
  acc[4] += bf_lo(v.z); acc[5] += bf_hi(v.z);
  acc[6] += bf_lo(v.w); acc[7] += bf_hi(v.w);
}

// ---------------- merged prep + bucket histogram ----------------
// blocks [0, nblocks): per-block bucket histogram of dst (int4 edge reads)
// blocks [nblocks, ...): convert x->bf16, transpose W1/W2/W3, zero dummy rows
__global__ void prep_hist_kernel(const int* __restrict__ dst, int* __restrict__ histG,
                                 int E, int nbuck, int nblocks,
                                 const float* __restrict__ x, ushort* __restrict__ xb,
                                 const float* __restrict__ W1, ushort* __restrict__ Wt1,
                                 const float* __restrict__ W2, ushort* __restrict__ Wt2,
                                 const float* __restrict__ W3, ushort* __restrict__ W3t,
                                 ushort* __restrict__ xbN, ushort* __restrict__ bufBN, int n4) {
  __shared__ int lh[512];
  int tid = threadIdx.x;
  if ((int)blockIdx.x < nblocks) {
    int blk = blockIdx.x;
    for (int i = tid; i < nbuck; i += 256) lh[i] = 0;
    __syncthreads();
    int base = blk * EPB + tid * 4;
#pragma unroll
    for (int it = 0; it < EPB / 1024; ++it) {
      int e = base + it * 1024;
      if (e + 3 < E) {
        int4 d4 = *(const int4*)(dst + e);
        atomicAdd(&lh[d4.x >> 8], 1);
        atomicAdd(&lh[d4.y >> 8], 1);
        atomicAdd(&lh[d4.z >> 8], 1);
        atomicAdd(&lh[d4.w >> 8], 1);
      } else {
#pragma unroll
        for (int q = 0; q < 4; ++q) {
          int ee = e + q;
          if (ee < E) atomicAdd(&lh[dst[ee] >> 8], 1);
        }
      }
    }
    __syncthreads();
    for (int i = tid; i < nbuck; i += 256) histG[(size_t)i * nblocks + blk] = lh[i];
    return;
  }
  int i = ((int)blockIdx.x - nblocks) * 256 + tid;
  if (i < n4) {
    float4 v = ((const float4*)x)[i];
    ushort4 o; o.x = f2bf(v.x); o.y = f2bf(v.y); o.z = f2bf(v.z); o.w = f2bf(v.w);
    ((ushort4*)xb)[i] = o;
    return;
  }
  int j = i - n4;
  if (j < DF * DF) {
    int nr = j >> 7, k = j & 127;
    Wt1[j] = f2bf(W1[(size_t)k * DF + nr]);
    return;
  }
  j -= DF * DF;
  if (j < DF * DF) {
    int nr = j >> 7, k = j & 127;
    Wt2[j] = f2bf(W2[(size_t)k * DF + nr]);
    return;
  }
  j -= DF * DF;
  if (j < 16 * DF) {
    int nr = j >> 7, k = j & 127;
    W3t[j] = (nr < 10) ? f2bf(W3[(size_t)k * 10 + nr]) : (ushort)0;
    return;
  }
  j -= 16 * DF;
  if (j < 16) { ((uint4*)xbN)[j] = (uint4){0, 0, 0, 0}; return; }
  j -= 16;
  if (j < 16) { ((uint4*)bufBN)[j] = (uint4){0, 0, 0, 0}; }
}

// ---------------- CSR build: scans + scatter + per-bucket sort ----------------

__global__ void scan1_kernel(const int* __restrict__ cnt, int* __restrict__ excl,
                             int* __restrict__ bsums, int n) {
  __shared__ int wsum[4];
  int t = threadIdx.x;
  int base = blockIdx.x * 1024 + t * 4;
  int v[4]; int s = 0;
#pragma unroll
  for (int i = 0; i < 4; i++) { int d = (base + i < n) ? cnt[base + i] : 0; v[i] = s; s += d; }
  int lane = t & 63, w = t >> 6;
  int sc = s;
#pragma unroll
  for (int off = 1; off < 64; off <<= 1) { int o = __shfl_up(sc, off); if (lane >= off) sc += o; }
  if (lane == 63) wsum[w] = sc;
  __syncthreads();
  int woff = 0;
  for (int i = 0; i < w; i++) woff += wsum[i];
  int toff = woff + (sc - s);
#pragma unroll
  for (int i = 0; i < 4; i++) if (base + i < n) excl[base + i] = toff + v[i];
  if (t == 255) bsums[blockIdx.x] = woff + sc;
}

__global__ void scan2_kernel(int* bsums, int nb) {
  __shared__ int wsum[16];
  int t = threadIdx.x;
  int v = (t < nb) ? bsums[t] : 0;
  int lane = t & 63, w = t >> 6;
  int sc = v;
#pragma unroll
  for (int off = 1; off < 64; off <<= 1) { int o = __shfl_up(sc, off); if (lane >= off) sc += o; }
  if (lane == 63) wsum[w] = sc;
  __syncthreads();
  int woff = 0;
  for (int i = 0; i < w; i++) woff += wsum[i];
  if (t < nb) bsums[t] = woff + sc - v;
}

__global__ void bucket_scatter_kernel(const int* __restrict__ src, const int* __restrict__ dst,
                                      const int* __restrict__ histE, const int* __restrict__ bsums,
                                      uint* __restrict__ eb, int E, int nbuck, int nblocks) {
  __shared__ int lc[512];
  int tid = threadIdx.x, blk = blockIdx.x;
  for (int i = tid; i < nbuck; i += 256) {
    int idx = i * nblocks + blk;
    lc[i] = histE[idx] + bsums[idx >> 10];
  }
  __syncthreads();
  int base = blk * EPB + tid * 4;
#pragma unroll
  for (int it = 0; it < EPB / 1024; ++it) {
    int e = base + it * 1024;
    if (e + 3 < E) {
      int4 s4 = *(const int4*)(src + e);
      int4 d4 = *(const int4*)(dst + e);
      int p0 = atomicAdd(&lc[d4.x >> 8], 1);
      eb[p0] = (uint)s4.x | ((uint)(d4.x & 255) << 24);
      int p1 = atomicAdd(&lc[d4.y >> 8], 1);
      eb[p1] = (uint)s4.y | ((uint)(d4.y & 255) << 24);
      int p2 = atomicAdd(&lc[d4.z >> 8], 1);
      eb[p2] = (uint)s4.z | ((uint)(d4.z & 255) << 24);
      int p3 = atomicAdd(&lc[d4.w >> 8], 1);
      eb[p3] = (uint)s4.w | ((uint)(d4.w & 255) << 24);
    } else {
#pragma unroll
      for (int q = 0; q < 4; ++q) {
        int ee = e + q;
        if (ee < E) {
          int d = dst[ee];
          int pos = atomicAdd(&lc[d >> 8], 1);
          eb[pos] = (uint)src[ee] | ((uint)(d & 255) << 24);
        }
      }
    }
  }
}

__global__ void bucket_sort_kernel(const uint* __restrict__ eb,
                                   const int* __restrict__ histE, const int* __restrict__ bsums,
                                   int* __restrict__ rowptr, int* __restrict__ csr,
                                   int N, int E, int nbuck, int nblocks) {
  __shared__ int cnt[256];
  __shared__ int cursor[256];
  __shared__ int wsum[4];
  int tid = threadIdx.x, b = blockIdx.x;
  int idx = b * nblocks;
  int beg = histE[idx] + bsums[idx >> 10];
  int end = E;
  if (b + 1 < nbuck) { int i2 = (b + 1) * nblocks; end = histE[i2] + bsums[i2 >> 10]; }
  cnt[tid] = 0;
  __syncthreads();
  for (int e = beg + tid; e < end; e += 256)
    atomicAdd(&cnt[eb[e] >> 24], 1);
  __syncthreads();
  int v = cnt[tid];
  int lane = tid & 63, w = tid >> 6;
  int sc = v;
#pragma unroll
  for (int off = 1; off < 64; off <<= 1) { int o = __shfl_up(sc, off); if (lane >= off) sc += o; }
  if (lane == 63) wsum[w] = sc;
  __syncthreads();
  int woff = 0;
  for (int i = 0; i < w; i++) woff += wsum[i];
  int excl = woff + sc - v;
  int node = (b << 8) + tid;
  if (node <= N) rowptr[node] = beg + excl;
  cursor[tid] = beg + excl;
  __syncthreads();
  for (int e = beg + tid; e < end; e += 256) {
    uint vv = eb[e];
    int pos = atomicAdd(&cursor[vv >> 24], 1);
    csr[pos] = (int)(vv & 0x00FFFFFFu);
  }
}

// ---------------- scatter-mean: one 16-lane group per node (4 nodes/wave) ----------------
// Each group loads 4 full 256B rows per iteration; OOR edges clamp to the
// all-zero row n (cache-resident). 32-bit byte offsets -> saddr loads.
// Measured at the random-gather path floor (~7 TB/s logical through L2/L3).
__global__ __launch_bounds__(256) void aggregate_kernel(
    const ushort* __restrict__ xb, const int* __restrict__ rowptr,
    const int* __restrict__ csr, ushort* __restrict__ out, int n) {
  int tid = threadIdx.x;
  int node = (blockIdx.x * 256 + tid) >> 4;
  if (node >= n) return;
  uint c16 = (uint)(tid & 15) * 16u;      // byte offset within 256B row
  int beg = rowptr[node], end = rowptr[node + 1];
  const char* xbase = (const char*)xb;
  float acc[8];
#pragma unroll
  for (int i = 0; i < 8; i++) acc[i] = 0.f;

#pragma unroll 1
  for (int e = beg; e < end; e += 4) {
    int e1 = e + 1, e2 = e + 2, e3 = e + 3;
    uint r0 = (uint)csr[e];
    uint r1 = (e1 < end) ? (uint)csr[e1] : (uint)n;
    uint r2 = (e2 < end) ? (uint)csr[e2] : (uint)n;
    uint r3 = (e3 < end) ? (uint)csr[e3] : (uint)n;
    uint4 v0 = *(const uint4*)(xbase + (r0 * 256u + c16));
    uint4 v1 = *(const uint4*)(xbase + (r1 * 256u + c16));
    uint4 v2 = *(const uint4*)(xbase + (r2 * 256u + c16));
    uint4 v3 = *(const uint4*)(xbase + (r3 * 256u + c16));
    addv8(acc, v0);
    addv8(acc, v1);
    addv8(acc, v2);
    addv8(acc, v3);
  }

  int deg = end - beg;
  uint4 r;
  if (deg > 0) {
    float inv = 1.0f / (float)deg;
    r.x = (uint)f2bf(acc[0] * inv) | ((uint)f2bf(acc[1] * inv) << 16);
    r.y = (uint)f2bf(acc[2] * inv) | ((uint)f2bf(acc[3] * inv) << 16);
    r.z = (uint)f2bf(acc[4] * inv) | ((uint)f2bf(acc[5] * inv) << 16);
    r.w = (uint)f2bf(acc[6] * inv) | ((uint)f2bf(acc[7] * inv) << 16);
  } else {
    r = *(const uint4*)(xbase + ((uint)node * 256u + c16));
  }
  *(uint4*)((char*)out + ((uint)node * 256u + c16)) = r;
}

// ---------------- GEMM1 [n x 128] @ W[128 x 128] + bias + tanh, bf16 MFMA ----------------
// A and W both staged in LDS (global-W variant measured 9us slower, r8).
__global__ __launch_bounds__(256) void gemm_tanh_mfma(
    const ushort* __restrict__ A, const ushort* __restrict__ Wt,
    const float* __restrict__ bias, ushort* __restrict__ out, int n) {
  __shared__ ushort As[64 * AST];
  __shared__ ushort Ws[128 * AST];
  int tid = threadIdx.x;
  int node0 = blockIdx.x * 64;

  for (int i = tid; i < 64 * 16; i += 256) {
    int r = i >> 4, c = i & 15;
    int node = node0 + r; if (node >= n) node = n - 1;
    uint4 v = ((const uint4*)(A + (size_t)node * DF))[c];
    *(uint4*)&As[r * AST + c * 8] = v;
  }
  for (int i = tid; i < 128 * 16; i += 256) {
    int r = i >> 4, c = i & 15;
    uint4 v = ((const uint4*)(Wt + r * DF))[c];
    *(uint4*)&Ws[r * AST + c * 8] = v;
  }
  __syncthreads();

  int lane = tid & 63, w = tid >> 6;
  int wr = (w >> 1) * 32;
  int wc = (w & 1) * 64;
  int r16 = lane & 15, g8 = (lane >> 4) * 8;

  f32x4 acc[2][4];
#pragma unroll
  for (int i = 0; i < 2; i++)
#pragma unroll
    for (int j = 0; j < 4; j++) acc[i][j] = (f32x4){0.f, 0.f, 0.f, 0.f};

#pragma unroll
  for (int ks = 0; ks < 4; ++ks) {
    int k0 = ks * 32 + g8;
    bf16x8 a0 = *(const bf16x8*)&As[(wr + r16) * AST + k0];
    bf16x8 a1 = *(const bf16x8*)&As[(wr + 16 + r16) * AST + k0];
#pragma unroll
    for (int j = 0; j < 4; j++) {
      bf16x8 b = *(const bf16x8*)&Ws[(wc + j * 16 + r16) * AST + k0];
      acc[0][j] = __builtin_amdgcn_mfma_f32_16x16x32_bf16(a0, b, acc[0][j], 0, 0, 0);
      acc[1][j] = __builtin_amdgcn_mfma_f32_16x16x32_bf16(a1, b, acc[1][j], 0, 0, 0);
    }
  }

#pragma unroll
  for (int mi = 0; mi < 2; mi++) {
#pragma unroll
    for (int j = 0; j < 4; j++) {
      int col = wc + j * 16 + r16;
      float bv = bias[col];
      int rowb = wr + mi * 16 + (lane >> 4) * 4;
#pragma unroll
      for (int q = 0; q < 4; q++) {
        int node = node0 + rowb + q;
        if (node < n) {
          float vv = tanhf(acc[mi][j][q] + bv);
          out[(size_t)node * DF + col] = f2bf(vv);
        }
      }
    }
  }
}

// ---------------- GEMM2 + head fused: h2 = tanh(A@W2+b2) -> LDS -> logits = h2@W3+b3
__global__ __launch_bounds__(256) void gemm2_head_mfma(
    const ushort* __restrict__ A, const ushort* __restrict__ Wt,
    const float* __restrict__ bias, const ushort* __restrict__ W3t,
    const float* __restrict__ b3, float* __restrict__ out, int n) {
  __shared__ ushort As[64 * AST];
  __shared__ ushort Ws[128 * AST];
  __shared__ ushort W3s[16 * AST];
  int tid = threadIdx.x;
  int node0 = blockIdx.x * 64;

  for (int i = tid; i < 64 * 16; i += 256) {
    int r = i >> 4, c = i & 15;
    int node = node0 + r; if (node >= n) node = n - 1;
    uint4 v = ((const uint4*)(A + (size_t)node * DF))[c];
    *(uint4*)&As[r * AST + c * 8] = v;
  }
  for (int i = tid; i < 128 * 16; i += 256) {
    int r = i >> 4, c = i & 15;
    uint4 v = ((const uint4*)(Wt + r * DF))[c];
    *(uint4*)&Ws[r * AST + c * 8] = v;
  }
  {
    int r = tid >> 4, c = tid & 15;
    uint4 v = ((const uint4*)(W3t + r * DF))[c];
    *(uint4*)&W3s[r * AST + c * 8] = v;
  }
  __syncthreads();

  int lane = tid & 63, w = tid >> 6;
  int wr = (w >> 1) * 32, wc = (w & 1) * 64;
  int r16 = lane & 15, g8 = (lane >> 4) * 8;

  f32x4 acc[2][4];
#pragma unroll
  for (int i = 0; i < 2; i++)
#pragma unroll
    for (int j = 0; j < 4; j++) acc[i][j] = (f32x4){0.f, 0.f, 0.f, 0.f};

#pragma unroll
  for (int ks = 0; ks < 4; ++ks) {
    int k0 = ks * 32 + g8;
    bf16x8 a0 = *(const bf16x8*)&As[(wr + r16) * AST + k0];
    bf16x8 a1 = *(const bf16x8*)&As[(wr + 16 + r16) * AST + k0];
#pragma unroll
    for (int j = 0; j < 4; ++j) {
      bf16x8 b = *(const bf16x8*)&Ws[(wc + j * 16 + r16) * AST + k0];
      acc[0][j] = __builtin_amdgcn_mfma_f32_16x16x32_bf16(a0, b, acc[0][j], 0, 0, 0);
      acc[1][j] = __builtin_amdgcn_mfma_f32_16x16x32_bf16(a1, b, acc[1][j], 0, 0, 0);
    }
  }

  __syncthreads();   // all As reads done; overwrite with h2
#pragma unroll
  for (int mi = 0; mi < 2; mi++) {
#pragma unroll
    for (int j = 0; j < 4; j++) {
      int col = wc + j * 16 + r16;
      float bv = bias[col];
      int rowb = wr + mi * 16 + (lane >> 4) * 4;
#pragma unroll
      for (int q = 0; q < 4; q++)
        As[(rowb + q) * AST + col] = f2bf(tanhf(acc[mi][j][q] + bv));
    }
  }
  __syncthreads();

  // head: wave w handles rows [w*16, w*16+16)
  f32x4 h = (f32x4){0.f, 0.f, 0.f, 0.f};
#pragma unroll
  for (int ks = 0; ks < 4; ++ks) {
    int k0 = ks * 32 + g8;
    bf16x8 a = *(const bf16x8*)&As[(w * 16 + r16) * AST + k0];
    bf16x8 b = *(const bf16x8*)&W3s[r16 * AST + k0];
    h = __builtin_amdgcn_mfma_f32_16x16x32_bf16(a, b, h, 0, 0, 0);
  }
  if (r16 < 10) {
    float bv = b3[r16];
    int rowb = w * 16 + (lane >> 4) * 4;
#pragma unroll
    for (int q = 0; q < 4; q++) {
      int node = node0 + rowb + q;
      if (node < n) out[(size_t)node * 10 + r16] = h[q] + bv;
    }
  }
}

extern "C" void kernel_launch(void* const* d_in, const int* in_sizes, int n_in,
                              void* d_out, int out_size, void* d_ws, size_t ws_size,
                              hipStream_t stream) {
  const float* x    = (const float*)d_in[0];
  const int*   esrc = (const int*)d_in[1];
  const int*   edst = (const int*)d_in[2];
  const float* W1   = (const float*)d_in[3];
  const float* b1   = (const float*)d_in[4];
  const float* W2   = (const float*)d_in[5];
  const float* b2   = (const float*)d_in[6];
  const float* W3   = (const float*)d_in[7];
  const float* b3   = (const float*)d_in[8];
  float* out = (float*)d_out;

  const int N = in_sizes[0] / DF;   // 100000
  const int E = in_sizes[1];        // 1600000

  const int nbuck   = (N + 255) >> 8;            // 391
  const int nblocks = (E + EPB - 1) / EPB;       // 782
  const int M = nbuck * nblocks;                 // ~306K

  // workspace layout
  char* ws = (char*)d_ws;
  int*  rowptr = (int*)ws;               // N+1
  int*  csr    = rowptr + (N + 1);       // E
  int*  histG  = csr + E;                // M
  int*  histE  = histG + M;              // M
  int*  bsums2 = histE + M;              // 1024
  uint* eb     = (uint*)(bsums2 + 1024); // E
  size_t off = (size_t)((char*)(eb + E) - ws);
  off = (off + 255) & ~(size_t)255;
  ushort* xb  = (ushort*)(ws + off);     off += (size_t)(N + 1) * DF * 2; off = (off + 255) & ~(size_t)255;
  ushort* Wt1 = (ushort*)(ws + off);     off += (size_t)DF * DF * 2;
  ushort* Wt2 = (ushort*)(ws + off);     off += (size_t)DF * DF * 2;
  ushort* W3t = (ushort*)(ws + off);     off += (size_t)16 * DF * 2; off = (off + 255) & ~(size_t)255;
  ushort* bufA = (ushort*)(ws + off);    off += (size_t)N * DF * 2; off = (off + 255) & ~(size_t)255;
  ushort* bufB = (ushort*)(ws + off);    // N+1 rows (zero row N)

  // merged prep + hist
  int n4 = N * DF / 4;
  int prep_total = n4 + 2 * DF * DF + 16 * DF + 32;
  int prep_blocks = (prep_total + 255) / 256;
  prep_hist_kernel<<<nblocks + prep_blocks, 256, 0, stream>>>(
      edst, histG, E, nbuck, nblocks,
      x, xb, W1, Wt1, W2, Wt2, W3, W3t,
      xb + (size_t)N * DF, bufB + (size_t)N * DF, n4);

  // CSR build
  int nb_m = (M + 1023) / 1024;
  scan1_kernel<<<nb_m, 256, 0, stream>>>(histG, histE, bsums2, M);
  scan2_kernel<<<1, 1024, 0, stream>>>(bsums2, nb_m);
  bucket_scatter_kernel<<<nblocks, 256, 0, stream>>>(esrc, edst, histE, bsums2, eb, E, nbuck, nblocks);
  bucket_sort_kernel<<<nbuck, 256, 0, stream>>>(eb, histE, bsums2, rowptr, csr, N, E, nbuck, nblocks);

  int agg_blocks = (N + 15) / 16;          // one 16-lane group per node
  int gemm_blocks = (N + 63) / 64;

  // layer 1
  aggregate_kernel<<<agg_blocks, 256, 0, stream>>>(xb, rowptr, csr, bufA, N);
  gemm_tanh_mfma<<<gemm_blocks, 256, 0, stream>>>(bufA, Wt1, b1, bufB, N);
  // layer 2 + head
  aggregate_kernel<<<agg_blocks, 256, 0, stream>>>(bufB, rowptr, csr, bufA, N);
  gemm2_head_mfma<<<gemm_blocks, 256, 0, stream>>>(bufA, Wt2, b2, W3t, b3, out, N);
}

// Round 10
// 210.912 us; speedup vs baseline: 1.1129x; 1.0522x over previous
//
#include <hip/hip_runtime.h>

#define DF 128
#define AST 136   // padded LDS row stride (bf16 elems)
#define EPB 2048  // edges per block in bucket passes

typedef float f32x4 __attribute__((ext_vector_type(4)));
typedef short bf16x8 __attribute__((ext_vector_type(8)));

__device__ __forceinline__ ushort f2bf(float f) {
  union { float f; uint u; } c; c.f = f;
  uint u = c.u;
  uint r = (u + 0x7fffu + ((u >> 16) & 1u)) >> 16;   // RNE
  return (ushort)r;
}
__device__ __forceinline__ float bf_lo(uint v) { union { uint u; float f; } c; c.u = v << 16; return c.f; }
__device__ __forceinline__ float bf_hi(uint v) { union { uint u; float f; } c; c.u = v & 0xffff0000u; return c.f; }

__device__ __forceinline__ void addv8(float* acc, uint4 v) {
  acc[0] += bf_lo(v.x); acc[1] += bf_hi(v.x);
  acc[2] += bf_lo(v.y); acc[3] += bf_hi(v.y);
  acc[4] += bf_lo(v.z); acc[5] += bf_hi(v.z);
  acc[6] += bf_lo(v.w); acc[7] += bf_hi(v.w);
}

// ---------------- merged prep + bucket histogram ----------------
__global__ void prep_hist_kernel(const int* __restrict__ dst, int* __restrict__ histG,
                                 int E, int nbuck, int nblocks,
                                 const float* __restrict__ x, ushort* __restrict__ xb,
                                 const float* __restrict__ W1, ushort* __restrict__ Wt1,
                                 const float* __restrict__ W2, ushort* __restrict__ Wt2,
                                 const float* __restrict__ W3, ushort* __restrict__ W3t,
                                 ushort* __restrict__ xbN, ushort* __restrict__ bufBN, int n4) {
  __shared__ int lh[512];
  int tid = threadIdx.x;
  if ((int)blockIdx.x < nblocks) {
    int blk = blockIdx.x;
    for (int i = tid; i < nbuck; i += 256) lh[i] = 0;
    __syncthreads();
    int base = blk * EPB + tid * 4;
#pragma unroll
    for (int it = 0; it < EPB / 1024; ++it) {
      int e = base + it * 1024;
      if (e + 3 < E) {
        int4 d4 = *(const int4*)(dst + e);
        atomicAdd(&lh[d4.x >> 8], 1);
        atomicAdd(&lh[d4.y >> 8], 1);
        atomicAdd(&lh[d4.z >> 8], 1);
        atomicAdd(&lh[d4.w >> 8], 1);
      } else {
#pragma unroll
        for (int q = 0; q < 4; ++q) {
          int ee = e + q;
          if (ee < E) atomicAdd(&lh[dst[ee] >> 8], 1);
        }
      }
    }
    __syncthreads();
    for (int i = tid; i < nbuck; i += 256) histG[(size_t)i * nblocks + blk] = lh[i];
    return;
  }
  int i = ((int)blockIdx.x - nblocks) * 256 + tid;
  if (i < n4) {
    float4 v = ((const float4*)x)[i];
    ushort4 o; o.x = f2bf(v.x); o.y = f2bf(v.y); o.z = f2bf(v.z); o.w = f2bf(v.w);
    ((ushort4*)xb)[i] = o;
    return;
  }
  int j = i - n4;
  if (j < DF * DF) {
    int nr = j >> 7, k = j & 127;
    Wt1[j] = f2bf(W1[(size_t)k * DF + nr]);
    return;
  }
  j -= DF * DF;
  if (j < DF * DF) {
    int nr = j >> 7, k = j & 127;
    Wt2[j] = f2bf(W2[(size_t)k * DF + nr]);
    return;
  }
  j -= DF * DF;
  if (j < 16 * DF) {
    int nr = j >> 7, k = j & 127;
    W3t[j] = (nr < 10) ? f2bf(W3[(size_t)k * 10 + nr]) : (ushort)0;
    return;
  }
  j -= 16 * DF;
  if (j < 16) { ((uint4*)xbN)[j] = (uint4){0, 0, 0, 0}; return; }
  j -= 16;
  if (j < 16) { ((uint4*)bufBN)[j] = (uint4){0, 0, 0, 0}; }
}

// ---------------- scan over per-(bucket,block) histogram ----------------
__global__ void scan1_kernel(const int* __restrict__ cnt, int* __restrict__ excl,
                             int* __restrict__ bsums, int n) {
  __shared__ int wsum[4];
  int t = threadIdx.x;
  int base = blockIdx.x * 1024 + t * 4;
  int v[4]; int s = 0;
#pragma unroll
  for (int i = 0; i < 4; i++) { int d = (base + i < n) ? cnt[base + i] : 0; v[i] = s; s += d; }
  int lane = t & 63, w = t >> 6;
  int sc = s;
#pragma unroll
  for (int off = 1; off < 64; off <<= 1) { int o = __shfl_up(sc, off); if (lane >= off) sc += o; }
  if (lane == 63) wsum[w] = sc;
  __syncthreads();
  int woff = 0;
  for (int i = 0; i < w; i++) woff += wsum[i];
  int toff = woff + (sc - s);
#pragma unroll
  for (int i = 0; i < 4; i++) if (base + i < n) excl[base + i] = toff + v[i];
  if (t == 255) bsums[blockIdx.x] = woff + sc;
}

// local exclusive scan of bsums[0..nb) into sbs[512] (nb <= 512), 256 threads
__device__ __forceinline__ void scan_bsums_lds(const int* __restrict__ bsums, int nb,
                                               int* sbs, int* wsum) {
  int t = threadIdx.x;
  int v0 = (2 * t < nb) ? bsums[2 * t] : 0;
  int v1 = (2 * t + 1 < nb) ? bsums[2 * t + 1] : 0;
  int s = v0 + v1;
  int lane = t & 63, w = t >> 6;
  int sc = s;
#pragma unroll
  for (int off = 1; off < 64; off <<= 1) { int o = __shfl_up(sc, off); if (lane >= off) sc += o; }
  if (lane == 63) wsum[w] = sc;
  __syncthreads();
  int woff = 0;
  for (int i = 0; i < w; i++) woff += wsum[i];
  int excl = woff + sc - s;
  sbs[2 * t] = excl;
  sbs[2 * t + 1] = excl + v0;
  __syncthreads();
}

// ---------------- scatter edges into bucket-contiguous packed array ----------------
__global__ void bucket_scatter_kernel(const int* __restrict__ src, const int* __restrict__ dst,
                                      const int* __restrict__ histE, const int* __restrict__ bsums,
                                      int nb, uint* __restrict__ eb, int E, int nbuck, int nblocks) {
  __shared__ int lc[512];
  __shared__ int sbs[512];
  __shared__ int wsum[4];
  int tid = threadIdx.x, blk = blockIdx.x;
  scan_bsums_lds(bsums, nb, sbs, wsum);
  for (int i = tid; i < nbuck; i += 256) {
    int idx = i * nblocks + blk;
    lc[i] = histE[idx] + sbs[idx >> 10];
  }
  __syncthreads();
  int base = blk * EPB + tid * 4;
#pragma unroll
  for (int it = 0; it < EPB / 1024; ++it) {
    int e = base + it * 1024;
    if (e + 3 < E) {
      int4 s4 = *(const int4*)(src + e);
      int4 d4 = *(const int4*)(dst + e);
      int p0 = atomicAdd(&lc[d4.x >> 8], 1);
      eb[p0] = (uint)s4.x | ((uint)(d4.x & 255) << 24);
      int p1 = atomicAdd(&lc[d4.y >> 8], 1);
      eb[p1] = (uint)s4.y | ((uint)(d4.y & 255) << 24);
      int p2 = atomicAdd(&lc[d4.z >> 8], 1);
      eb[p2] = (uint)s4.z | ((uint)(d4.z & 255) << 24);
      int p3 = atomicAdd(&lc[d4.w >> 8], 1);
      eb[p3] = (uint)s4.w | ((uint)(d4.w & 255) << 24);
    } else {
#pragma unroll
      for (int q = 0; q < 4; ++q) {
        int ee = e + q;
        if (ee < E) {
          int d = dst[ee];
          int pos = atomicAdd(&lc[d >> 8], 1);
          eb[pos] = (uint)src[ee] | ((uint)(d & 255) << 24);
        }
      }
    }
  }
}

// ---------------- one block per bucket: counting sort, emit rowptr + csr ----------------
__global__ void bucket_sort_kernel(const uint* __restrict__ eb,
                                   const int* __restrict__ histE, const int* __restrict__ bsums,
                                   int nb, int* __restrict__ rowptr, int* __restrict__ csr,
                                   int N, int E, int nbuck, int nblocks) {
  __shared__ int cnt[256];
  __shared__ int cursor[256];
  __shared__ int sbs[512];
  __shared__ int wsum[4];
  int tid = threadIdx.x, b = blockIdx.x;
  scan_bsums_lds(bsums, nb, sbs, wsum);
  int idx = b * nblocks;
  int beg = histE[idx] + sbs[idx >> 10];
  int end = E;
  if (b + 1 < nbuck) { int i2 = (b + 1) * nblocks; end = histE[i2] + sbs[i2 >> 10]; }
  cnt[tid] = 0;
  __syncthreads();
  for (int e = beg + tid; e < end; e += 256)
    atomicAdd(&cnt[eb[e] >> 24], 1);
  __syncthreads();
  int v = cnt[tid];
  int lane = tid & 63, w = tid >> 6;
  int sc = v;
#pragma unroll
  for (int off = 1; off < 64; off <<= 1) { int o = __shfl_up(sc, off); if (lane >= off) sc += o; }
  if (lane == 63) wsum[w] = sc;
  __syncthreads();
  int woff = 0;
  for (int i = 0; i < w; i++) woff += wsum[i];
  int excl = woff + sc - v;
  int node = (b << 8) + tid;
  if (node <= N) rowptr[node] = beg + excl;
  cursor[tid] = beg + excl;
  __syncthreads();
  for (int e = beg + tid; e < end; e += 256) {
    uint vv = eb[e];
    int pos = atomicAdd(&cursor[vv >> 24], 1);
    csr[pos] = (int)(vv & 0x00FFFFFFu);
  }
}

// ---------------- scatter-mean: one 16-lane group per node, software-pipelined ----------------
__global__ __launch_bounds__(256) void aggregate_kernel(
    const ushort* __restrict__ xb, const int* __restrict__ rowptr,
    const int* __restrict__ csr, ushort* __restrict__ out, int n) {
  int tid = threadIdx.x;
  int node = (blockIdx.x * 256 + tid) >> 4;
  if (node >= n) return;
  uint c16 = (uint)(tid & 15) * 16u;      // byte offset within 256B row
  int beg = rowptr[node], end = rowptr[node + 1];
  const char* xbase = (const char*)xb;
  float acc[8];
#pragma unroll
  for (int i = 0; i < 8; i++) acc[i] = 0.f;
  int deg = end - beg;

  if (deg > 0) {
    uint4 v0, v1, v2, v3;
    {
      int e = beg;
      uint r0 = (uint)csr[e];
      uint r1 = (e + 1 < end) ? (uint)csr[e + 1] : (uint)n;
      uint r2 = (e + 2 < end) ? (uint)csr[e + 2] : (uint)n;
      uint r3 = (e + 3 < end) ? (uint)csr[e + 3] : (uint)n;
      v0 = *(const uint4*)(xbase + (r0 * 256u + c16));
      v1 = *(const uint4*)(xbase + (r1 * 256u + c16));
      v2 = *(const uint4*)(xbase + (r2 * 256u + c16));
      v3 = *(const uint4*)(xbase + (r3 * 256u + c16));
    }
#pragma unroll 1
    for (int e = beg + 4; e < end; e += 4) {
      uint r0 = (uint)csr[e];
      uint r1 = (e + 1 < end) ? (uint)csr[e + 1] : (uint)n;
      uint r2 = (e + 2 < end) ? (uint)csr[e + 2] : (uint)n;
      uint r3 = (e + 3 < end) ? (uint)csr[e + 3] : (uint)n;
      uint4 n0 = *(const uint4*)(xbase + (r0 * 256u + c16));
      uint4 n1 = *(const uint4*)(xbase + (r1 * 256u + c16));
      uint4 n2 = *(const uint4*)(xbase + (r2 * 256u + c16));
      uint4 n3 = *(const uint4*)(xbase + (r3 * 256u + c16));
      addv8(acc, v0); addv8(acc, v1); addv8(acc, v2); addv8(acc, v3);
      v0 = n0; v1 = n1; v2 = n2; v3 = n3;
    }
    addv8(acc, v0); addv8(acc, v1); addv8(acc, v2); addv8(acc, v3);
  }

  uint4 r;
  if (deg > 0) {
    float inv = 1.0f / (float)deg;
    r.x = (uint)f2bf(acc[0] * inv) | ((uint)f2bf(acc[1] * inv) << 16);
    r.y = (uint)f2bf(acc[2] * inv) | ((uint)f2bf(acc[3] * inv) << 16);
    r.z = (uint)f2bf(acc[4] * inv) | ((uint)f2bf(acc[5] * inv) << 16);
    r.w = (uint)f2bf(acc[6] * inv) | ((uint)f2bf(acc[7] * inv) << 16);
  } else {
    r = *(const uint4*)(xbase + ((uint)node * 256u + c16));
  }
  *(uint4*)((char*)out + ((uint)node * 256u + c16)) = r;
}

// ---------------- persistent GEMM1: stage W once, loop A-tiles ----------------
__global__ __launch_bounds__(256) void gemm_tanh_mfma(
    const ushort* __restrict__ A, const ushort* __restrict__ Wt,
    const float* __restrict__ bias, ushort* __restrict__ out, int n, int ntiles) {
  __shared__ ushort As[64 * AST];
  __shared__ ushort Ws[128 * AST];
  __shared__ float bs[128];
  int tid = threadIdx.x;

  for (int i = tid; i < 128 * 16; i += 256) {
    int r = i >> 4, c = i & 15;
    uint4 v = ((const uint4*)(Wt + r * DF))[c];
    *(uint4*)&Ws[r * AST + c * 8] = v;
  }
  if (tid < 128) bs[tid] = bias[tid];

  int lane = tid & 63, w = tid >> 6;
  int wr = (w >> 1) * 32;
  int wc = (w & 1) * 64;
  int r16 = lane & 15, g8 = (lane >> 4) * 8;

  for (int tile = blockIdx.x; tile < ntiles; tile += gridDim.x) {
    int node0 = tile * 64;
    __syncthreads();   // prev-iter As reads done (also covers Ws/bs first time)
    for (int i = tid; i < 64 * 16; i += 256) {
      int r = i >> 4, c = i & 15;
      int node = node0 + r; if (node >= n) node = n - 1;
      uint4 v = ((const uint4*)(A + (size_t)node * DF))[c];
      *(uint4*)&As[r * AST + c * 8] = v;
    }
    __syncthreads();

    f32x4 acc[2][4];
#pragma unroll
    for (int i = 0; i < 2; i++)
#pragma unroll
      for (int j = 0; j < 4; j++) acc[i][j] = (f32x4){0.f, 0.f, 0.f, 0.f};

#pragma unroll
    for (int ks = 0; ks < 4; ++ks) {
      int k0 = ks * 32 + g8;
      bf16x8 a0 = *(const bf16x8*)&As[(wr + r16) * AST + k0];
      bf16x8 a1 = *(const bf16x8*)&As[(wr + 16 + r16) * AST + k0];
#pragma unroll
      for (int j = 0; j < 4; j++) {
        bf16x8 b = *(const bf16x8*)&Ws[(wc + j * 16 + r16) * AST + k0];
        acc[0][j] = __builtin_amdgcn_mfma_f32_16x16x32_bf16(a0, b, acc[0][j], 0, 0, 0);
        acc[1][j] = __builtin_amdgcn_mfma_f32_16x16x32_bf16(a1, b, acc[1][j], 0, 0, 0);
      }
    }

#pragma unroll
    for (int mi = 0; mi < 2; mi++) {
#pragma unroll
      for (int j = 0; j < 4; j++) {
        int col = wc + j * 16 + r16;
        float bv = bs[col];
        int rowb = wr + mi * 16 + (lane >> 4) * 4;
#pragma unroll
        for (int q = 0; q < 4; q++) {
          int node = node0 + rowb + q;
          if (node < n) {
            float vv = tanhf(acc[mi][j][q] + bv);
            out[(size_t)node * DF + col] = f2bf(vv);
          }
        }
      }
    }
  }
}

// ---------------- persistent GEMM2 + head ----------------
__global__ __launch_bounds__(256) void gemm2_head_mfma(
    const ushort* __restrict__ A, const ushort* __restrict__ Wt,
    const float* __restrict__ bias, const ushort* __restrict__ W3t,
    const float* __restrict__ b3, float* __restrict__ out, int n, int ntiles) {
  __shared__ ushort As[64 * AST];
  __shared__ ushort Ws[128 * AST];
  __shared__ ushort W3s[16 * AST];
  __shared__ float bs[128];
  int tid = threadIdx.x;

  for (int i = tid; i < 128 * 16; i += 256) {
    int r = i >> 4, c = i & 15;
    uint4 v = ((const uint4*)(Wt + r * DF))[c];
    *(uint4*)&Ws[r * AST + c * 8] = v;
  }
  {
    int r = tid >> 4, c = tid & 15;
    uint4 v = ((const uint4*)(W3t + r * DF))[c];
    *(uint4*)&W3s[r * AST + c * 8] = v;
  }
  if (tid < 128) bs[tid] = bias[tid];

  int lane = tid & 63, w = tid >> 6;
  int wr = (w >> 1) * 32, wc = (w & 1) * 64;
  int r16 = lane & 15, g8 = (lane >> 4) * 8;

  for (int tile = blockIdx.x; tile < ntiles; tile += gridDim.x) {
    int node0 = tile * 64;
    __syncthreads();   // prev-iter As(h2) reads done
    for (int i = tid; i < 64 * 16; i += 256) {
      int r = i >> 4, c = i & 15;
      int node = node0 + r; if (node >= n) node = n - 1;
      uint4 v = ((const uint4*)(A + (size_t)node * DF))[c];
      *(uint4*)&As[r * AST + c * 8] = v;
    }
    __syncthreads();

    f32x4 acc[2][4];
#pragma unroll
    for (int i = 0; i < 2; i++)
#pragma unroll
      for (int j = 0; j < 4; j++) acc[i][j] = (f32x4){0.f, 0.f, 0.f, 0.f};

#pragma unroll
    for (int ks = 0; ks < 4; ++ks) {
      int k0 = ks * 32 + g8;
      bf16x8 a0 = *(const bf16x8*)&As[(wr + r16) * AST + k0];
      bf16x8 a1 = *(const bf16x8*)&As[(wr + 16 + r16) * AST + k0];
#pragma unroll
      for (int j = 0; j < 4; ++j) {
        bf16x8 b = *(const bf16x8*)&Ws[(wc + j * 16 + r16) * AST + k0];
        acc[0][j] = __builtin_amdgcn_mfma_f32_16x16x32_bf16(a0, b, acc[0][j], 0, 0, 0);
        acc[1][j] = __builtin_amdgcn_mfma_f32_16x16x32_bf16(a1, b, acc[1][j], 0, 0, 0);
      }
    }

    __syncthreads();   // all As reads done; overwrite with h2
#pragma unroll
    for (int mi = 0; mi < 2; mi++) {
#pragma unroll
      for (int j = 0; j < 4; j++) {
        int col = wc + j * 16 + r16;
        float bv = bs[col];
        int rowb = wr + mi * 16 + (lane >> 4) * 4;
#pragma unroll
        for (int q = 0; q < 4; q++)
          As[(rowb + q) * AST + col] = f2bf(tanhf(acc[mi][j][q] + bv));
      }
    }
    __syncthreads();

    f32x4 h = (f32x4){0.f, 0.f, 0.f, 0.f};
#pragma unroll
    for (int ks = 0; ks < 4; ++ks) {
      int k0 = ks * 32 + g8;
      bf16x8 a = *(const bf16x8*)&As[(w * 16 + r16) * AST + k0];
      bf16x8 b = *(const bf16x8*)&W3s[r16 * AST + k0];
      h = __builtin_amdgcn_mfma_f32_16x16x32_bf16(a, b, h, 0, 0, 0);
    }
    if (r16 < 10) {
      float bv = b3[r16];
      int rowb = w * 16 + (lane >> 4) * 4;
#pragma unroll
      for (int q = 0; q < 4; q++) {
        int node = node0 + rowb + q;
        if (node < n) out[(size_t)node * 10 + r16] = h[q] + bv;
      }
    }
  }
}

extern "C" void kernel_launch(void* const* d_in, const int* in_sizes, int n_in,
                              void* d_out, int out_size, void* d_ws, size_t ws_size,
                              hipStream_t stream) {
  const float* x    = (const float*)d_in[0];
  const int*   esrc = (const int*)d_in[1];
  const int*   edst = (const int*)d_in[2];
  const float* W1   = (const float*)d_in[3];
  const float* b1   = (const float*)d_in[4];
  const float* W2   = (const float*)d_in[5];
  const float* b2   = (const float*)d_in[6];
  const float* W3   = (const float*)d_in[7];
  const float* b3   = (const float*)d_in[8];
  float* out = (float*)d_out;

  const int N = in_sizes[0] / DF;   // 100000
  const int E = in_sizes[1];        // 1600000

  const int nbuck   = (N + 255) >> 8;            // 391
  const int nblocks = (E + EPB - 1) / EPB;       // 782
  const int M = nbuck * nblocks;                 // ~306K

  // workspace layout
  char* ws = (char*)d_ws;
  int*  rowptr = (int*)ws;               // N+1
  int*  csr    = rowptr + (N + 1);       // E
  int*  histG  = csr + E;                // M
  int*  histE  = histG + M;              // M
  int*  bsums2 = histE + M;              // 1024
  uint* eb     = (uint*)(bsums2 + 1024); // E
  size_t off = (size_t)((char*)(eb + E) - ws);
  off = (off + 255) & ~(size_t)255;
  ushort* xb  = (ushort*)(ws + off);     off += (size_t)(N + 1) * DF * 2; off = (off + 255) & ~(size_t)255;
  ushort* Wt1 = (ushort*)(ws + off);     off += (size_t)DF * DF * 2;
  ushort* Wt2 = (ushort*)(ws + off);     off += (size_t)DF * DF * 2;
  ushort* W3t = (ushort*)(ws + off);     off += (size_t)16 * DF * 2; off = (off + 255) & ~(size_t)255;
  ushort* bufA = (ushort*)(ws + off);    off += (size_t)N * DF * 2; off = (off + 255) & ~(size_t)255;
  ushort* bufB = (ushort*)(ws + off);    // N+1 rows (zero row N)

  // merged prep + hist
  int n4 = N * DF / 4;
  int prep_total = n4 + 2 * DF * DF + 16 * DF + 32;
  int prep_blocks = (prep_total + 255) / 256;
  prep_hist_kernel<<<nblocks + prep_blocks, 256, 0, stream>>>(
      edst, histG, E, nbuck, nblocks,
      x, xb, W1, Wt1, W2, Wt2, W3, W3t,
      xb + (size_t)N * DF, bufB + (size_t)N * DF, n4);

  // CSR build (scan2 folded into scatter/sort)
  int nb_m = (M + 1023) / 1024;
  scan1_kernel<<<nb_m, 256, 0, stream>>>(histG, histE, bsums2, M);
  bucket_scatter_kernel<<<nblocks, 256, 0, stream>>>(esrc, edst, histE, bsums2, nb_m, eb, E, nbuck, nblocks);
  bucket_sort_kernel<<<nbuck, 256, 0, stream>>>(eb, histE, bsums2, nb_m, rowptr, csr, N, E, nbuck, nblocks);

  int agg_blocks = (N + 15) / 16;          // one 16-lane group per node
  int ntiles = (N + 63) / 64;
  int gemm_grid = ntiles < 512 ? ntiles : 512;

  // layer 1
  aggregate_kernel<<<agg_blocks, 256, 0, stream>>>(xb, rowptr, csr, bufA, N);
  gemm_tanh_mfma<<<gemm_grid, 256, 0, stream>>>(bufA, Wt1, b1, bufB, N, ntiles);
  // layer 2 + head
  aggregate_kernel<<<agg_blocks, 256, 0, stream>>>(bufB, rowptr, csr, bufA, N);
  gemm2_head_mfma<<<gemm_grid, 256, 0, stream>>>(bufA, Wt2, b2, W3t, b3, out, N, ntiles);
}

// Round 11
// 204.398 us; speedup vs baseline: 1.1483x; 1.0319x over previous
//
#include <hip/hip_runtime.h>

#define DF 128
#define AST 136   // padded LDS row stride (bf16 elems)
#define EPB 4096  // edges per block in bucket passes

typedef float f32x4 __attribute__((ext_vector_type(4)));
typedef short bf16x8 __attribute__((ext_vector_type(8)));

__device__ __forceinline__ ushort f2bf(float f) {
  union { float f; uint u; } c; c.f = f;
  uint u = c.u;
  uint r = (u + 0x7fffu + ((u >> 16) & 1u)) >> 16;   // RNE
  return (ushort)r;
}
__device__ __forceinline__ float bf_lo(uint v) { union { uint u; float f; } c; c.u = v << 16; return c.f; }
__device__ __forceinline__ float bf_hi(uint v) { union { uint u; float f; } c; c.u = v & 0xffff0000u; return c.f; }

__device__ __forceinline__ void addv8(float* acc, uint4 v) {
  acc[0] += bf_lo(v.x); acc[1] += bf_hi(v.x);
  acc[2] += bf_lo(v.y); acc[3] += bf_hi(v.y);
  acc[4] += bf_lo(v.z); acc[5] += bf_hi(v.z);
  acc[6] += bf_lo(v.w); acc[7] += bf_hi(v.w);
}

// ---------------- merged prep + bucket histogram ----------------
__global__ void prep_hist_kernel(const int* __restrict__ dst, int* __restrict__ histG,
                                 int E, int nbuck, int nblocks,
                                 const float* __restrict__ x, ushort* __restrict__ xb,
                                 const float* __restrict__ W1, ushort* __restrict__ Wt1,
                                 const float* __restrict__ W2, ushort* __restrict__ Wt2,
                                 const float* __restrict__ W3, ushort* __restrict__ W3t,
                                 ushort* __restrict__ xbN, ushort* __restrict__ bufBN, int n4) {
  __shared__ int lh[512];
  int tid = threadIdx.x;
  if ((int)blockIdx.x < nblocks) {
    int blk = blockIdx.x;
    for (int i = tid; i < nbuck; i += 256) lh[i] = 0;
    __syncthreads();
    int base = blk * EPB + tid * 4;
#pragma unroll
    for (int it = 0; it < EPB / 1024; ++it) {
      int e = base + it * 1024;
      if (e + 3 < E) {
        int4 d4 = *(const int4*)(dst + e);
        atomicAdd(&lh[d4.x >> 8], 1);
        atomicAdd(&lh[d4.y >> 8], 1);
        atomicAdd(&lh[d4.z >> 8], 1);
        atomicAdd(&lh[d4.w >> 8], 1);
      } else {
#pragma unroll
        for (int q = 0; q < 4; ++q) {
          int ee = e + q;
          if (ee < E) atomicAdd(&lh[dst[ee] >> 8], 1);
        }
      }
    }
    __syncthreads();
    for (int i = tid; i < nbuck; i += 256) histG[(size_t)i * nblocks + blk] = lh[i];
    return;
  }
  int i = ((int)blockIdx.x - nblocks) * 256 + tid;
  if (i < n4) {
    float4 v = ((const float4*)x)[i];
    ushort4 o; o.x = f2bf(v.x); o.y = f2bf(v.y); o.z = f2bf(v.z); o.w = f2bf(v.w);
    ((ushort4*)xb)[i] = o;
    return;
  }
  int j = i - n4;
  if (j < DF * DF) {
    int nr = j >> 7, k = j & 127;
    Wt1[j] = f2bf(W1[(size_t)k * DF + nr]);
    return;
  }
  j -= DF * DF;
  if (j < DF * DF) {
    int nr = j >> 7, k = j & 127;
    Wt2[j] = f2bf(W2[(size_t)k * DF + nr]);
    return;
  }
  j -= DF * DF;
  if (j < 16 * DF) {
    int nr = j >> 7, k = j & 127;
    W3t[j] = (nr < 10) ? f2bf(W3[(size_t)k * 10 + nr]) : (ushort)0;
    return;
  }
  j -= 16 * DF;
  if (j < 16) { ((uint4*)xbN)[j] = (uint4){0, 0, 0, 0}; return; }
  j -= 16;
  if (j < 16) { ((uint4*)bufBN)[j] = (uint4){0, 0, 0, 0}; }
}

// ---------------- scan over per-(bucket,block) histogram ----------------
__global__ void scan1_kernel(const int* __restrict__ cnt, int* __restrict__ excl,
                             int* __restrict__ bsums, int n) {
  __shared__ int wsum[4];
  int t = threadIdx.x;
  int base = blockIdx.x * 1024 + t * 4;
  int v[4]; int s = 0;
#pragma unroll
  for (int i = 0; i < 4; i++) { int d = (base + i < n) ? cnt[base + i] : 0; v[i] = s; s += d; }
  int lane = t & 63, w = t >> 6;
  int sc = s;
#pragma unroll
  for (int off = 1; off < 64; off <<= 1) { int o = __shfl_up(sc, off); if (lane >= off) sc += o; }
  if (lane == 63) wsum[w] = sc;
  __syncthreads();
  int woff = 0;
  for (int i = 0; i < w; i++) woff += wsum[i];
  int toff = woff + (sc - s);
#pragma unroll
  for (int i = 0; i < 4; i++) if (base + i < n) excl[base + i] = toff + v[i];
  if (t == 255) bsums[blockIdx.x] = woff + sc;
}

// local exclusive scan of bsums[0..nb) into sbs[512] (nb <= 512), 256 threads
__device__ __forceinline__ void scan_bsums_lds(const int* __restrict__ bsums, int nb,
                                               int* sbs, int* wsum) {
  int t = threadIdx.x;
  int v0 = (2 * t < nb) ? bsums[2 * t] : 0;
  int v1 = (2 * t + 1 < nb) ? bsums[2 * t + 1] : 0;
  int s = v0 + v1;
  int lane = t & 63, w = t >> 6;
  int sc = s;
#pragma unroll
  for (int off = 1; off < 64; off <<= 1) { int o = __shfl_up(sc, off); if (lane >= off) sc += o; }
  if (lane == 63) wsum[w] = sc;
  __syncthreads();
  int woff = 0;
  for (int i = 0; i < w; i++) woff += wsum[i];
  int excl = woff + sc - s;
  sbs[2 * t] = excl;
  sbs[2 * t + 1] = excl + v0;
  __syncthreads();
}

// ---------------- scatter edges into bucket-contiguous packed array ----------------
__global__ void bucket_scatter_kernel(const int* __restrict__ src, const int* __restrict__ dst,
                                      const int* __restrict__ histE, const int* __restrict__ bsums,
                                      int nb, uint* __restrict__ eb, int E, int nbuck, int nblocks) {
  __shared__ int lc[512];
  __shared__ int sbs[512];
  __shared__ int wsum[4];
  int tid = threadIdx.x, blk = blockIdx.x;
  scan_bsums_lds(bsums, nb, sbs, wsum);
  for (int i = tid; i < nbuck; i += 256) {
    int idx = i * nblocks + blk;
    lc[i] = histE[idx] + sbs[idx >> 10];
  }
  __syncthreads();
  int base = blk * EPB + tid * 4;
#pragma unroll
  for (int it = 0; it < EPB / 1024; ++it) {
    int e = base + it * 1024;
    if (e + 3 < E) {
      int4 s4 = *(const int4*)(src + e);
      int4 d4 = *(const int4*)(dst + e);
      int p0 = atomicAdd(&lc[d4.x >> 8], 1);
      eb[p0] = (uint)s4.x | ((uint)(d4.x & 255) << 24);
      int p1 = atomicAdd(&lc[d4.y >> 8], 1);
      eb[p1] = (uint)s4.y | ((uint)(d4.y & 255) << 24);
      int p2 = atomicAdd(&lc[d4.z >> 8], 1);
      eb[p2] = (uint)s4.z | ((uint)(d4.z & 255) << 24);
      int p3 = atomicAdd(&lc[d4.w >> 8], 1);
      eb[p3] = (uint)s4.w | ((uint)(d4.w & 255) << 24);
    } else {
#pragma unroll
      for (int q = 0; q < 4; ++q) {
        int ee = e + q;
        if (ee < E) {
          int d = dst[ee];
          int pos = atomicAdd(&lc[d >> 8], 1);
          eb[pos] = (uint)src[ee] | ((uint)(d & 255) << 24);
        }
      }
    }
  }
}

// ---------------- one block per bucket: counting sort, emit rowptr + csr ----------------
__global__ void bucket_sort_kernel(const uint* __restrict__ eb,
                                   const int* __restrict__ histE, const int* __restrict__ bsums,
                                   int nb, int* __restrict__ rowptr, int* __restrict__ csr,
                                   int N, int E, int nbuck, int nblocks) {
  __shared__ int cnt[256];
  __shared__ int cursor[256];
  __shared__ int sbs[512];
  __shared__ int wsum[4];
  int tid = threadIdx.x, b = blockIdx.x;
  scan_bsums_lds(bsums, nb, sbs, wsum);
  int idx = b * nblocks;
  int beg = histE[idx] + sbs[idx >> 10];
  int end = E;
  if (b + 1 < nbuck) { int i2 = (b + 1) * nblocks; end = histE[i2] + sbs[i2 >> 10]; }
  cnt[tid] = 0;
  __syncthreads();
  for (int e = beg + tid; e < end; e += 256)
    atomicAdd(&cnt[eb[e] >> 24], 1);
  __syncthreads();
  int v = cnt[tid];
  int lane = tid & 63, w = tid >> 6;
  int sc = v;
#pragma unroll
  for (int off = 1; off < 64; off <<= 1) { int o = __shfl_up(sc, off); if (lane >= off) sc += o; }
  if (lane == 63) wsum[w] = sc;
  __syncthreads();
  int woff = 0;
  for (int i = 0; i < w; i++) woff += wsum[i];
  int excl = woff + sc - v;
  int node = (b << 8) + tid;
  if (node <= N) rowptr[node] = beg + excl;
  cursor[tid] = beg + excl;
  __syncthreads();
  for (int e = beg + tid; e < end; e += 256) {
    uint vv = eb[e];
    int pos = atomicAdd(&cursor[vv >> 24], 1);
    csr[pos] = (int)(vv & 0x00FFFFFFu);
  }
}

// ---------------- scatter-mean: one 16-lane group per node (at L3 path floor) ----------------
__global__ __launch_bounds__(256) void aggregate_kernel(
    const ushort* __restrict__ xb, const int* __restrict__ rowptr,
    const int* __restrict__ csr, ushort* __restrict__ out, int n) {
  int tid = threadIdx.x;
  int node = (blockIdx.x * 256 + tid) >> 4;
  if (node >= n) return;
  uint c16 = (uint)(tid & 15) * 16u;      // byte offset within 256B row
  int beg = rowptr[node], end = rowptr[node + 1];
  const char* xbase = (const char*)xb;
  float acc[8];
#pragma unroll
  for (int i = 0; i < 8; i++) acc[i] = 0.f;

#pragma unroll 1
  for (int e = beg; e < end; e += 4) {
    int e1 = e + 1, e2 = e + 2, e3 = e + 3;
    uint r0 = (uint)csr[e];
    uint r1 = (e1 < end) ? (uint)csr[e1] : (uint)n;
    uint r2 = (e2 < end) ? (uint)csr[e2] : (uint)n;
    uint r3 = (e3 < end) ? (uint)csr[e3] : (uint)n;
    uint4 v0 = *(const uint4*)(xbase + (r0 * 256u + c16));
    uint4 v1 = *(const uint4*)(xbase + (r1 * 256u + c16));
    uint4 v2 = *(const uint4*)(xbase + (r2 * 256u + c16));
    uint4 v3 = *(const uint4*)(xbase + (r3 * 256u + c16));
    addv8(acc, v0);
    addv8(acc, v1);
    addv8(acc, v2);
    addv8(acc, v3);
  }

  int deg = end - beg;
  uint4 r;
  if (deg > 0) {
    float inv = 1.0f / (float)deg;
    r.x = (uint)f2bf(acc[0] * inv) | ((uint)f2bf(acc[1] * inv) << 16);
    r.y = (uint)f2bf(acc[2] * inv) | ((uint)f2bf(acc[3] * inv) << 16);
    r.z = (uint)f2bf(acc[4] * inv) | ((uint)f2bf(acc[5] * inv) << 16);
    r.w = (uint)f2bf(acc[6] * inv) | ((uint)f2bf(acc[7] * inv) << 16);
  } else {
    r = *(const uint4*)(xbase + ((uint)node * 256u + c16));
  }
  *(uint4*)((char*)out + ((uint)node * 256u + c16)) = r;
}

// ---------------- persistent GEMM1: W in LDS, A read directly (no reuse -> no staging) ----------
__global__ __launch_bounds__(256) void gemm_tanh_mfma(
    const ushort* __restrict__ A, const ushort* __restrict__ Wt,
    const float* __restrict__ bias, ushort* __restrict__ out, int n, int ntiles) {
  __shared__ ushort Ws[128 * AST];
  __shared__ float bs[128];
  int tid = threadIdx.x;

  for (int i = tid; i < 128 * 16; i += 256) {
    int r = i >> 4, c = i & 15;
    uint4 v = ((const uint4*)(Wt + r * DF))[c];
    *(uint4*)&Ws[r * AST + c * 8] = v;
  }
  if (tid < 128) bs[tid] = bias[tid];
  __syncthreads();

  int lane = tid & 63, w = tid >> 6;
  int wr = (w >> 1) * 32;
  int wc = (w & 1) * 64;
  int r16 = lane & 15, g8 = (lane >> 4) * 8;

  for (int tile = blockIdx.x; tile < ntiles; tile += gridDim.x) {
    int node0 = tile * 64;
    int ra = node0 + wr + r16;      if (ra >= n) ra = n - 1;
    int rb = node0 + wr + 16 + r16; if (rb >= n) rb = n - 1;
    const ushort* pa = A + (size_t)ra * DF + g8;
    const ushort* pb = A + (size_t)rb * DF + g8;

    f32x4 acc[2][4];
#pragma unroll
    for (int i = 0; i < 2; i++)
#pragma unroll
      for (int j = 0; j < 4; j++) acc[i][j] = (f32x4){0.f, 0.f, 0.f, 0.f};

#pragma unroll
    for (int ks = 0; ks < 4; ++ks) {
      bf16x8 a0 = *(const bf16x8*)(pa + ks * 32);
      bf16x8 a1 = *(const bf16x8*)(pb + ks * 32);
      int k0 = ks * 32 + g8;
#pragma unroll
      for (int j = 0; j < 4; j++) {
        bf16x8 b = *(const bf16x8*)&Ws[(wc + j * 16 + r16) * AST + k0];
        acc[0][j] = __builtin_amdgcn_mfma_f32_16x16x32_bf16(a0, b, acc[0][j], 0, 0, 0);
        acc[1][j] = __builtin_amdgcn_mfma_f32_16x16x32_bf16(a1, b, acc[1][j], 0, 0, 0);
      }
    }

#pragma unroll
    for (int mi = 0; mi < 2; mi++) {
#pragma unroll
      for (int j = 0; j < 4; j++) {
        int col = wc + j * 16 + r16;
        float bv = bs[col];
        int rowb = wr + mi * 16 + (lane >> 4) * 4;
#pragma unroll
        for (int q = 0; q < 4; q++) {
          int node = node0 + rowb + q;
          if (node < n) {
            float vv = tanhf(acc[mi][j][q] + bv);
            out[(size_t)node * DF + col] = f2bf(vv);
          }
        }
      }
    }
  }
}

// ---------------- persistent GEMM2 + head: A direct, h2 via LDS transpose ----------------
__global__ __launch_bounds__(256) void gemm2_head_mfma(
    const ushort* __restrict__ A, const ushort* __restrict__ Wt,
    const float* __restrict__ bias, const ushort* __restrict__ W3t,
    const float* __restrict__ b3, float* __restrict__ out, int n, int ntiles) {
  __shared__ ushort Hs[64 * AST];
  __shared__ ushort Ws[128 * AST];
  __shared__ ushort W3s[16 * AST];
  __shared__ float bs[128];
  int tid = threadIdx.x;

  for (int i = tid; i < 128 * 16; i += 256) {
    int r = i >> 4, c = i & 15;
    uint4 v = ((const uint4*)(Wt + r * DF))[c];
    *(uint4*)&Ws[r * AST + c * 8] = v;
  }
  {
    int r = tid >> 4, c = tid & 15;
    uint4 v = ((const uint4*)(W3t + r * DF))[c];
    *(uint4*)&W3s[r * AST + c * 8] = v;
  }
  if (tid < 128) bs[tid] = bias[tid];
  __syncthreads();

  int lane = tid & 63, w = tid >> 6;
  int wr = (w >> 1) * 32, wc = (w & 1) * 64;
  int r16 = lane & 15, g8 = (lane >> 4) * 8;

  for (int tile = blockIdx.x; tile < ntiles; tile += gridDim.x) {
    int node0 = tile * 64;
    int ra = node0 + wr + r16;      if (ra >= n) ra = n - 1;
    int rb = node0 + wr + 16 + r16; if (rb >= n) rb = n - 1;
    const ushort* pa = A + (size_t)ra * DF + g8;
    const ushort* pb = A + (size_t)rb * DF + g8;

    f32x4 acc[2][4];
#pragma unroll
    for (int i = 0; i < 2; i++)
#pragma unroll
      for (int j = 0; j < 4; j++) acc[i][j] = (f32x4){0.f, 0.f, 0.f, 0.f};

#pragma unroll
    for (int ks = 0; ks < 4; ++ks) {
      bf16x8 a0 = *(const bf16x8*)(pa + ks * 32);
      bf16x8 a1 = *(const bf16x8*)(pb + ks * 32);
      int k0 = ks * 32 + g8;
#pragma unroll
      for (int j = 0; j < 4; ++j) {
        bf16x8 b = *(const bf16x8*)&Ws[(wc + j * 16 + r16) * AST + k0];
        acc[0][j] = __builtin_amdgcn_mfma_f32_16x16x32_bf16(a0, b, acc[0][j], 0, 0, 0);
        acc[1][j] = __builtin_amdgcn_mfma_f32_16x16x32_bf16(a1, b, acc[1][j], 0, 0, 0);
      }
    }

    __syncthreads();   // prev-iter head reads of Hs done
#pragma unroll
    for (int mi = 0; mi < 2; mi++) {
#pragma unroll
      for (int j = 0; j < 4; j++) {
        int col = wc + j * 16 + r16;
        float bv = bs[col];
        int rowb = wr + mi * 16 + (lane >> 4) * 4;
#pragma unroll
        for (int q = 0; q < 4; q++)
          Hs[(rowb + q) * AST + col] = f2bf(tanhf(acc[mi][j][q] + bv));
      }
    }
    __syncthreads();

    f32x4 h = (f32x4){0.f, 0.f, 0.f, 0.f};
#pragma unroll
    for (int ks = 0; ks < 4; ++ks) {
      int k0 = ks * 32 + g8;
      bf16x8 a = *(const bf16x8*)&Hs[(w * 16 + r16) * AST + k0];
      bf16x8 b = *(const bf16x8*)&W3s[r16 * AST + k0];
      h = __builtin_amdgcn_mfma_f32_16x16x32_bf16(a, b, h, 0, 0, 0);
    }
    if (r16 < 10) {
      float bv = b3[r16];
      int rowb = w * 16 + (lane >> 4) * 4;
#pragma unroll
      for (int q = 0; q < 4; q++) {
        int node = node0 + rowb + q;
        if (node < n) out[(size_t)node * 10 + r16] = h[q] + bv;
      }
    }
  }
}

extern "C" void kernel_launch(void* const* d_in, const int* in_sizes, int n_in,
                              void* d_out, int out_size, void* d_ws, size_t ws_size,
                              hipStream_t stream) {
  const float* x    = (const float*)d_in[0];
  const int*   esrc = (const int*)d_in[1];
  const int*   edst = (const int*)d_in[2];
  const float* W1   = (const float*)d_in[3];
  const float* b1   = (const float*)d_in[4];
  const float* W2   = (const float*)d_in[5];
  const float* b2   = (const float*)d_in[6];
  const float* W3   = (const float*)d_in[7];
  const float* b3   = (const float*)d_in[8];
  float* out = (float*)d_out;

  const int N = in_sizes[0] / DF;   // 100000
  const int E = in_sizes[1];        // 1600000

  const int nbuck   = (N + 255) >> 8;            // 391
  const int nblocks = (E + EPB - 1) / EPB;       // 391
  const int M = nbuck * nblocks;                 // ~153K

  // workspace layout
  char* ws = (char*)d_ws;
  int*  rowptr = (int*)ws;               // N+1
  int*  csr    = rowptr + (N + 1);       // E
  int*  histG  = csr + E;                // M
  int*  histE  = histG + M;              // M
  int*  bsums2 = histE + M;              // 1024
  uint* eb     = (uint*)(bsums2 + 1024); // E
  size_t off = (size_t)((char*)(eb + E) - ws);
  off = (off + 255) & ~(size_t)255;
  ushort* xb  = (ushort*)(ws + off);     off += (size_t)(N + 1) * DF * 2; off = (off + 255) & ~(size_t)255;
  ushort* Wt1 = (ushort*)(ws + off);     off += (size_t)DF * DF * 2;
  ushort* Wt2 = (ushort*)(ws + off);     off += (size_t)DF * DF * 2;
  ushort* W3t = (ushort*)(ws + off);     off += (size_t)16 * DF * 2; off = (off + 255) & ~(size_t)255;
  ushort* bufA = (ushort*)(ws + off);    off += (size_t)N * DF * 2; off = (off + 255) & ~(size_t)255;
  ushort* bufB = (ushort*)(ws + off);    // N+1 rows (zero row N)

  // merged prep + hist
  int n4 = N * DF / 4;
  int prep_total = n4 + 2 * DF * DF + 16 * DF + 32;
  int prep_blocks = (prep_total + 255) / 256;
  prep_hist_kernel<<<nblocks + prep_blocks, 256, 0, stream>>>(
      edst, histG, E, nbuck, nblocks,
      x, xb, W1, Wt1, W2, Wt2, W3, W3t,
      xb + (size_t)N * DF, bufB + (size_t)N * DF, n4);

  // CSR build (scan2 folded into scatter/sort)
  int nb_m = (M + 1023) / 1024;
  scan1_kernel<<<nb_m, 256, 0, stream>>>(histG, histE, bsums2, M);
  bucket_scatter_kernel<<<nblocks, 256, 0, stream>>>(esrc, edst, histE, bsums2, nb_m, eb, E, nbuck, nblocks);
  bucket_sort_kernel<<<nbuck, 256, 0, stream>>>(eb, histE, bsums2, nb_m, rowptr, csr, N, E, nbuck, nblocks);

  int agg_blocks = (N + 15) / 16;          // one 16-lane group per node
  int ntiles = (N + 63) / 64;
  int gemm_grid = ntiles < 512 ? ntiles : 512;

  // layer 1
  aggregate_kernel<<<agg_blocks, 256, 0, stream>>>(xb, rowptr, csr, bufA, N);
  gemm_tanh_mfma<<<gemm_grid, 256, 0, stream>>>(bufA, Wt1, b1, bufB, N, ntiles);
  // layer 2 + head
  aggregate_kernel<<<agg_blocks, 256, 0, stream>>>(bufB, rowptr, csr, bufA, N);
  gemm2_head_mfma<<<gemm_grid, 256, 0, stream>>>(bufA, Wt2, b2, W3t, b3, out, N, ntiles);
}

// Round 12
// 197.365 us; speedup vs baseline: 1.1893x; 1.0356x over previous
//
#include <hip/hip_runtime.h>

#define DF 128
#define AST 136   // padded LDS row stride (bf16 elems)
#define EPB 4096  // edges per block in bucket passes

typedef float f32x4 __attribute__((ext_vector_type(4)));
typedef short bf16x8 __attribute__((ext_vector_type(8)));

__device__ __forceinline__ ushort f2bf(float f) {
  union { float f; uint u; } c; c.f = f;
  uint u = c.u;
  uint r = (u + 0x7fffu + ((u >> 16) & 1u)) >> 16;   // RNE
  return (ushort)r;
}
__device__ __forceinline__ float bf_lo(uint v) { union { uint u; float f; } c; c.u = v << 16; return c.f; }
__device__ __forceinline__ float bf_hi(uint v) { union { uint u; float f; } c; c.u = v & 0xffff0000u; return c.f; }

__device__ __forceinline__ void addv8(float* acc, uint4 v) {
  acc[0] += bf_lo(v.x); acc[1] += bf_hi(v.x);
  acc[2] += bf_lo(v.y); acc[3] += bf_hi(v.y);
  acc[4] += bf_lo(v.z); acc[5] += bf_hi(v.z);
  acc[6] += bf_lo(v.w); acc[7] += bf_hi(v.w);
}

// ---------------- merged prep + bucket histogram ----------------
__global__ void prep_hist_kernel(const int* __restrict__ dst, int* __restrict__ histG,
                                 int E, int nbuck, int nblocks,
                                 const float* __restrict__ x, ushort* __restrict__ xb,
                                 const float* __restrict__ W1, ushort* __restrict__ Wt1,
                                 const float* __restrict__ W2, ushort* __restrict__ Wt2,
                                 ushort* __restrict__ zbN, ushort* __restrict__ ybN, int n4) {
  __shared__ int lh[512];
  int tid = threadIdx.x;
  if ((int)blockIdx.x < nblocks) {
    int blk = blockIdx.x;
    for (int i = tid; i < nbuck; i += 256) lh[i] = 0;
    __syncthreads();
    int base = blk * EPB + tid * 4;
#pragma unroll
    for (int it = 0; it < EPB / 1024; ++it) {
      int e = base + it * 1024;
      if (e + 3 < E) {
        int4 d4 = *(const int4*)(dst + e);
        atomicAdd(&lh[d4.x >> 8], 1);
        atomicAdd(&lh[d4.y >> 8], 1);
        atomicAdd(&lh[d4.z >> 8], 1);
        atomicAdd(&lh[d4.w >> 8], 1);
      } else {
#pragma unroll
        for (int q = 0; q < 4; ++q) {
          int ee = e + q;
          if (ee < E) atomicAdd(&lh[dst[ee] >> 8], 1);
        }
      }
    }
    __syncthreads();
    for (int i = tid; i < nbuck; i += 256) histG[(size_t)i * nblocks + blk] = lh[i];
    return;
  }
  int i = ((int)blockIdx.x - nblocks) * 256 + tid;
  if (i < n4) {
    float4 v = ((const float4*)x)[i];
    ushort4 o; o.x = f2bf(v.x); o.y = f2bf(v.y); o.z = f2bf(v.z); o.w = f2bf(v.w);
    ((ushort4*)xb)[i] = o;
    return;
  }
  int j = i - n4;
  if (j < DF * DF) {
    int nr = j >> 7, k = j & 127;
    Wt1[j] = f2bf(W1[(size_t)k * DF + nr]);
    return;
  }
  j -= DF * DF;
  if (j < DF * DF) {
    int nr = j >> 7, k = j & 127;
    Wt2[j] = f2bf(W2[(size_t)k * DF + nr]);
    return;
  }
  j -= DF * DF;
  if (j < 16) { ((uint4*)zbN)[j] = (uint4){0, 0, 0, 0}; return; }
  j -= 16;
  if (j < 16) { ((uint4*)ybN)[j] = (uint4){0, 0, 0, 0}; }
}

// ---------------- shared GEMM tile body: out = A @ Ws (bf16, no bias) ----------------
__device__ __forceinline__ void gemm_tiles(const ushort* __restrict__ A,
                                           const ushort* __restrict__ Ws,
                                           ushort* __restrict__ out, int n, int ntiles,
                                           int tile0, int tstride, int tid) {
  int lane = tid & 63, w = tid >> 6;
  int wr = (w >> 1) * 32, wc = (w & 1) * 64;
  int r16 = lane & 15, g8 = (lane >> 4) * 8;
  for (int tile = tile0; tile < ntiles; tile += tstride) {
    int node0 = tile * 64;
    int ra = node0 + wr + r16;      if (ra >= n) ra = n - 1;
    int rb = node0 + wr + 16 + r16; if (rb >= n) rb = n - 1;
    const ushort* pa = A + (size_t)ra * DF + g8;
    const ushort* pb = A + (size_t)rb * DF + g8;

    f32x4 acc[2][4];
#pragma unroll
    for (int i = 0; i < 2; i++)
#pragma unroll
      for (int j = 0; j < 4; j++) acc[i][j] = (f32x4){0.f, 0.f, 0.f, 0.f};

#pragma unroll
    for (int ks = 0; ks < 4; ++ks) {
      bf16x8 a0 = *(const bf16x8*)(pa + ks * 32);
      bf16x8 a1 = *(const bf16x8*)(pb + ks * 32);
      int k0 = ks * 32 + g8;
#pragma unroll
      for (int j = 0; j < 4; j++) {
        bf16x8 b = *(const bf16x8*)&Ws[(wc + j * 16 + r16) * AST + k0];
        acc[0][j] = __builtin_amdgcn_mfma_f32_16x16x32_bf16(a0, b, acc[0][j], 0, 0, 0);
        acc[1][j] = __builtin_amdgcn_mfma_f32_16x16x32_bf16(a1, b, acc[1][j], 0, 0, 0);
      }
    }

#pragma unroll
    for (int mi = 0; mi < 2; mi++) {
#pragma unroll
      for (int j = 0; j < 4; j++) {
        int col = wc + j * 16 + r16;
        int rowb = wr + mi * 16 + (lane >> 4) * 4;
#pragma unroll
        for (int q = 0; q < 4; q++) {
          int node = node0 + rowb + q;
          if (node < n) out[(size_t)node * DF + col] = f2bf(acc[mi][j][q]);
        }
      }
    }
  }
}

// ---------------- role-split: scan1 (blocks < nb_m) || gemm_y = xb @ W1 ----------------
__global__ __launch_bounds__(256) void scan1_gemm_kernel(
    const int* __restrict__ cnt, int* __restrict__ excl, int* __restrict__ bsums, int Mn,
    int nb_m, const ushort* __restrict__ xb, const ushort* __restrict__ Wt1,
    ushort* __restrict__ yb, int n, int ntiles) {
  __shared__ ushort Ws[128 * AST];
  __shared__ int wsum[4];
  int t = threadIdx.x;
  if ((int)blockIdx.x < nb_m) {
    int base = blockIdx.x * 1024 + t * 4;
    int v[4]; int s = 0;
#pragma unroll
    for (int i = 0; i < 4; i++) { int d = (base + i < Mn) ? cnt[base + i] : 0; v[i] = s; s += d; }
    int lane = t & 63, w = t >> 6;
    int sc = s;
#pragma unroll
    for (int off = 1; off < 64; off <<= 1) { int o = __shfl_up(sc, off); if (lane >= off) sc += o; }
    if (lane == 63) wsum[w] = sc;
    __syncthreads();
    int woff = 0;
    for (int i = 0; i < w; i++) woff += wsum[i];
    int toff = woff + (sc - s);
#pragma unroll
    for (int i = 0; i < 4; i++) if (base + i < Mn) excl[base + i] = toff + v[i];
    if (t == 255) bsums[blockIdx.x] = woff + sc;
    return;
  }
  // gemm role
  for (int i = t; i < 128 * 16; i += 256) {
    int r = i >> 4, c = i & 15;
    uint4 v = ((const uint4*)(Wt1 + r * DF))[c];
    *(uint4*)&Ws[r * AST + c * 8] = v;
  }
  __syncthreads();
  gemm_tiles(xb, Ws, yb, n, ntiles, (int)blockIdx.x - nb_m, (int)gridDim.x - nb_m, t);
}

// ---------------- standalone persistent GEMM: zb = h1 @ W2 ----------------
__global__ __launch_bounds__(256) void gemm_plain_kernel(
    const ushort* __restrict__ A, const ushort* __restrict__ Wt,
    ushort* __restrict__ out, int n, int ntiles) {
  __shared__ ushort Ws[128 * AST];
  int t = threadIdx.x;
  for (int i = t; i < 128 * 16; i += 256) {
    int r = i >> 4, c = i & 15;
    uint4 v = ((const uint4*)(Wt + r * DF))[c];
    *(uint4*)&Ws[r * AST + c * 8] = v;
  }
  __syncthreads();
  gemm_tiles(A, Ws, out, n, ntiles, blockIdx.x, gridDim.x, t);
}

// local exclusive scan of bsums[0..nb) into sbs[512] (nb <= 512), 256 threads
__device__ __forceinline__ void scan_bsums_lds(const int* __restrict__ bsums, int nb,
                                               int* sbs, int* wsum) {
  int t = threadIdx.x;
  int v0 = (2 * t < nb) ? bsums[2 * t] : 0;
  int v1 = (2 * t + 1 < nb) ? bsums[2 * t + 1] : 0;
  int s = v0 + v1;
  int lane = t & 63, w = t >> 6;
  int sc = s;
#pragma unroll
  for (int off = 1; off < 64; off <<= 1) { int o = __shfl_up(sc, off); if (lane >= off) sc += o; }
  if (lane == 63) wsum[w] = sc;
  __syncthreads();
  int woff = 0;
  for (int i = 0; i < w; i++) woff += wsum[i];
  int excl = woff + sc - s;
  sbs[2 * t] = excl;
  sbs[2 * t + 1] = excl + v0;
  __syncthreads();
}

// ---------------- scatter edges into bucket-contiguous packed array ----------------
__global__ void bucket_scatter_kernel(const int* __restrict__ src, const int* __restrict__ dst,
                                      const int* __restrict__ histE, const int* __restrict__ bsums,
                                      int nb, uint* __restrict__ eb, int E, int nbuck, int nblocks) {
  __shared__ int lc[512];
  __shared__ int sbs[512];
  __shared__ int wsum[4];
  int tid = threadIdx.x, blk = blockIdx.x;
  scan_bsums_lds(bsums, nb, sbs, wsum);
  for (int i = tid; i < nbuck; i += 256) {
    int idx = i * nblocks + blk;
    lc[i] = histE[idx] + sbs[idx >> 10];
  }
  __syncthreads();
  int base = blk * EPB + tid * 4;
#pragma unroll
  for (int it = 0; it < EPB / 1024; ++it) {
    int e = base + it * 1024;
    if (e + 3 < E) {
      int4 s4 = *(const int4*)(src + e);
      int4 d4 = *(const int4*)(dst + e);
      int p0 = atomicAdd(&lc[d4.x >> 8], 1);
      eb[p0] = (uint)s4.x | ((uint)(d4.x & 255) << 24);
      int p1 = atomicAdd(&lc[d4.y >> 8], 1);
      eb[p1] = (uint)s4.y | ((uint)(d4.y & 255) << 24);
      int p2 = atomicAdd(&lc[d4.z >> 8], 1);
      eb[p2] = (uint)s4.z | ((uint)(d4.z & 255) << 24);
      int p3 = atomicAdd(&lc[d4.w >> 8], 1);
      eb[p3] = (uint)s4.w | ((uint)(d4.w & 255) << 24);
    } else {
#pragma unroll
      for (int q = 0; q < 4; ++q) {
        int ee = e + q;
        if (ee < E) {
          int d = dst[ee];
          int pos = atomicAdd(&lc[d >> 8], 1);
          eb[pos] = (uint)src[ee] | ((uint)(d & 255) << 24);
        }
      }
    }
  }
}

// ---------------- one block per bucket: counting sort, emit rowptr + csr ----------------
__global__ void bucket_sort_kernel(const uint* __restrict__ eb,
                                   const int* __restrict__ histE, const int* __restrict__ bsums,
                                   int nb, int* __restrict__ rowptr, int* __restrict__ csr,
                                   int N, int E, int nbuck, int nblocks) {
  __shared__ int cnt[256];
  __shared__ int cursor[256];
  __shared__ int sbs[512];
  __shared__ int wsum[4];
  int tid = threadIdx.x, b = blockIdx.x;
  scan_bsums_lds(bsums, nb, sbs, wsum);
  int idx = b * nblocks;
  int beg = histE[idx] + sbs[idx >> 10];
  int end = E;
  if (b + 1 < nbuck) { int i2 = (b + 1) * nblocks; end = histE[i2] + sbs[i2 >> 10]; }
  cnt[tid] = 0;
  __syncthreads();
  for (int e = beg + tid; e < end; e += 256)
    atomicAdd(&cnt[eb[e] >> 24], 1);
  __syncthreads();
  int v = cnt[tid];
  int lane = tid & 63, w = tid >> 6;
  int sc = v;
#pragma unroll
  for (int off = 1; off < 64; off <<= 1) { int o = __shfl_up(sc, off); if (lane >= off) sc += o; }
  if (lane == 63) wsum[w] = sc;
  __syncthreads();
  int woff = 0;
  for (int i = 0; i < w; i++) woff += wsum[i];
  int excl = woff + sc - v;
  int node = (b << 8) + tid;
  if (node <= N) rowptr[node] = beg + excl;
  cursor[tid] = beg + excl;
  __syncthreads();
  for (int e = beg + tid; e < end; e += 256) {
    uint vv = eb[e];
    int pos = atomicAdd(&cursor[vv >> 24], 1);
    csr[pos] = (int)(vv & 0x00FFFFFFu);
  }
}

// ---------------- gather-mean core: acc[8] per 16-lane group ----------------
__device__ __forceinline__ void gather_mean(const ushort* __restrict__ src,
                                            const int* __restrict__ rowptr,
                                            const int* __restrict__ csr,
                                            int node, int n, uint c16, float* acc) {
  int beg = rowptr[node], end = rowptr[node + 1];
  const char* xbase = (const char*)src;
#pragma unroll
  for (int i = 0; i < 8; i++) acc[i] = 0.f;
  int deg = end - beg;
  if (deg > 0) {
#pragma unroll 1
    for (int e = beg; e < end; e += 4) {
      int e1 = e + 1, e2 = e + 2, e3 = e + 3;
      uint r0 = (uint)csr[e];
      uint r1 = (e1 < end) ? (uint)csr[e1] : (uint)n;
      uint r2 = (e2 < end) ? (uint)csr[e2] : (uint)n;
      uint r3 = (e3 < end) ? (uint)csr[e3] : (uint)n;
      uint4 v0 = *(const uint4*)(xbase + (r0 * 256u + c16));
      uint4 v1 = *(const uint4*)(xbase + (r1 * 256u + c16));
      uint4 v2 = *(const uint4*)(xbase + (r2 * 256u + c16));
      uint4 v3 = *(const uint4*)(xbase + (r3 * 256u + c16));
      addv8(acc, v0);
      addv8(acc, v1);
      addv8(acc, v2);
      addv8(acc, v3);
    }
    float inv = 1.0f / (float)deg;
#pragma unroll
    for (int i = 0; i < 8; i++) acc[i] *= inv;
  } else {
    uint4 v = *(const uint4*)(xbase + ((uint)node * 256u + c16));
    float t[8] = {0, 0, 0, 0, 0, 0, 0, 0};
    addv8(t, v);
#pragma unroll
    for (int i = 0; i < 8; i++) acc[i] = t[i];
  }
}

// ---------------- agg1: h1 = tanh(mean_or_self(yb) + b1) ----------------
__global__ __launch_bounds__(256) void agg_bias_tanh_kernel(
    const ushort* __restrict__ yb, const int* __restrict__ rowptr,
    const int* __restrict__ csr, const float* __restrict__ bias,
    ushort* __restrict__ h1, int n) {
  int tid = threadIdx.x;
  int node = (blockIdx.x * 256 + tid) >> 4;
  if (node >= n) return;
  uint c16 = (uint)(tid & 15) * 16u;
  float acc[8];
  gather_mean(yb, rowptr, csr, node, n, c16, acc);
  int d8 = (tid & 15) * 8;
  float4 bA = *(const float4*)(bias + d8);
  float4 bB = *(const float4*)(bias + d8 + 4);
  float h0 = tanhf(acc[0] + bA.x), hh1 = tanhf(acc[1] + bA.y);
  float h2 = tanhf(acc[2] + bA.z), h3 = tanhf(acc[3] + bA.w);
  float h4 = tanhf(acc[4] + bB.x), h5 = tanhf(acc[5] + bB.y);
  float h6 = tanhf(acc[6] + bB.z), h7 = tanhf(acc[7] + bB.w);
  uint4 r;
  r.x = (uint)f2bf(h0) | ((uint)f2bf(hh1) << 16);
  r.y = (uint)f2bf(h2) | ((uint)f2bf(h3) << 16);
  r.z = (uint)f2bf(h4) | ((uint)f2bf(h5) << 16);
  r.w = (uint)f2bf(h6) | ((uint)f2bf(h7) << 16);
  *(uint4*)((char*)h1 + ((uint)node * 256u + c16)) = r;
}

// ---------------- agg2 + head: logits = tanh(mean_or_self(zb)+b2) @ W3 + b3 ----------------
__global__ __launch_bounds__(256) void agg_head_kernel(
    const ushort* __restrict__ zb, const int* __restrict__ rowptr,
    const int* __restrict__ csr, const float* __restrict__ b2,
    const float* __restrict__ W3, const float* __restrict__ b3,
    float* __restrict__ out, int n) {
  __shared__ float W3s[DF * 10];
  int tid = threadIdx.x;
  for (int i = tid; i < DF * 10; i += 256) W3s[i] = W3[i];
  __syncthreads();
  int node = (blockIdx.x * 256 + tid) >> 4;
  if (node >= n) return;
  uint c16 = (uint)(tid & 15) * 16u;
  float acc[8];
  gather_mean(zb, rowptr, csr, node, n, c16, acc);
  int d8 = (tid & 15) * 8;
  float4 bA = *(const float4*)(b2 + d8);
  float4 bB = *(const float4*)(b2 + d8 + 4);
  float h[8];
  h[0] = tanhf(acc[0] + bA.x); h[1] = tanhf(acc[1] + bA.y);
  h[2] = tanhf(acc[2] + bA.z); h[3] = tanhf(acc[3] + bA.w);
  h[4] = tanhf(acc[4] + bB.x); h[5] = tanhf(acc[5] + bB.y);
  h[6] = tanhf(acc[6] + bB.z); h[7] = tanhf(acc[7] + bB.w);
  float part[10];
#pragma unroll
  for (int j = 0; j < 10; j++) part[j] = 0.f;
#pragma unroll
  for (int i = 0; i < 8; i++) {
    const float* wrow = &W3s[(d8 + i) * 10];
#pragma unroll
    for (int j = 0; j < 10; j++) part[j] += h[i] * wrow[j];
  }
#pragma unroll
  for (int j = 0; j < 10; j++) {
    part[j] += __shfl_xor(part[j], 1);
    part[j] += __shfl_xor(part[j], 2);
    part[j] += __shfl_xor(part[j], 4);
    part[j] += __shfl_xor(part[j], 8);
  }
  int l16 = tid & 15;
#pragma unroll
  for (int j = 0; j < 10; j++)
    if (l16 == j) out[(size_t)node * 10 + j] = part[j] + b3[j];
}

extern "C" void kernel_launch(void* const* d_in, const int* in_sizes, int n_in,
                              void* d_out, int out_size, void* d_ws, size_t ws_size,
                              hipStream_t stream) {
  const float* x    = (const float*)d_in[0];
  const int*   esrc = (const int*)d_in[1];
  const int*   edst = (const int*)d_in[2];
  const float* W1   = (const float*)d_in[3];
  const float* b1   = (const float*)d_in[4];
  const float* W2   = (const float*)d_in[5];
  const float* b2   = (const float*)d_in[6];
  const float* W3   = (const float*)d_in[7];
  const float* b3   = (const float*)d_in[8];
  float* out = (float*)d_out;

  const int N = in_sizes[0] / DF;   // 100000
  const int E = in_sizes[1];        // 1600000

  const int nbuck   = (N + 255) >> 8;            // 391
  const int nblocks = (E + EPB - 1) / EPB;       // 391
  const int M = nbuck * nblocks;                 // ~153K

  // workspace layout
  char* ws = (char*)d_ws;
  int*  rowptr = (int*)ws;               // N+1
  int*  csr    = rowptr + (N + 1);       // E
  int*  histG  = csr + E;                // M
  int*  histE  = histG + M;              // M
  int*  bsums2 = histE + M;              // 1024
  uint* eb     = (uint*)(bsums2 + 1024); // E
  size_t off = (size_t)((char*)(eb + E) - ws);
  off = (off + 255) & ~(size_t)255;
  ushort* xb  = (ushort*)(ws + off);     off += (size_t)(N + 1) * DF * 2; off = (off + 255) & ~(size_t)255;  // doubles as zb
  ushort* Wt1 = (ushort*)(ws + off);     off += (size_t)DF * DF * 2;
  ushort* Wt2 = (ushort*)(ws + off);     off += (size_t)DF * DF * 2; off = (off + 255) & ~(size_t)255;
  ushort* yb  = (ushort*)(ws + off);     off += (size_t)(N + 1) * DF * 2; off = (off + 255) & ~(size_t)255;
  ushort* h1  = (ushort*)(ws + off);
  ushort* zb  = xb;   // xb is dead after gemm_y; reuse (row N zeroed in prep)

  // merged prep + hist
  int n4 = N * DF / 4;
  int prep_total = n4 + 2 * DF * DF + 32;
  int prep_blocks = (prep_total + 255) / 256;
  prep_hist_kernel<<<nblocks + prep_blocks, 256, 0, stream>>>(
      edst, histG, E, nbuck, nblocks,
      x, xb, W1, Wt1, W2, Wt2,
      xb + (size_t)N * DF, yb + (size_t)N * DF, n4);

  int nb_m = (M + 1023) / 1024;
  int ntiles = (N + 63) / 64;

  // scan1 || gemm_y = xb @ W1
  scan1_gemm_kernel<<<nb_m + 512, 256, 0, stream>>>(
      histG, histE, bsums2, M, nb_m, xb, Wt1, yb, N, ntiles);

  bucket_scatter_kernel<<<nblocks, 256, 0, stream>>>(esrc, edst, histE, bsums2, nb_m, eb, E, nbuck, nblocks);
  bucket_sort_kernel<<<nbuck, 256, 0, stream>>>(eb, histE, bsums2, nb_m, rowptr, csr, N, E, nbuck, nblocks);

  int agg_blocks = (N + 15) / 16;

  // layer 1: h1 = tanh(mean_or_self(yb) + b1)
  agg_bias_tanh_kernel<<<agg_blocks, 256, 0, stream>>>(yb, rowptr, csr, b1, h1, N);
  // layer 2 GEMM: zb = h1 @ W2
  gemm_plain_kernel<<<512, 256, 0, stream>>>(h1, Wt2, zb, N, ntiles);
  // layer 2 aggregate + head
  agg_head_kernel<<<agg_blocks, 256, 0, stream>>>(zb, rowptr, csr, b2, W3, b3, out, N);
}

// Round 14
// 187.728 us; speedup vs baseline: 1.2503x; 1.0513x over previous
//
#include <hip/hip_runtime.h>

#define DF 128
#define AST 136   // padded LDS row stride (bf16 elems)
#define EPB 4096  // edges per block in bucket passes

typedef float f32x4 __attribute__((ext_vector_type(4)));
typedef short bf16x8 __attribute__((ext_vector_type(8)));

__device__ __forceinline__ ushort f2bf(float f) {
  union { float f; uint u; } c; c.f = f;
  uint u = c.u;
  uint r = (u + 0x7fffu + ((u >> 16) & 1u)) >> 16;   // RNE
  return (ushort)r;
}
__device__ __forceinline__ float bf_lo(uint v) { union { uint u; float f; } c; c.u = v << 16; return c.f; }
__device__ __forceinline__ float bf_hi(uint v) { union { uint u; float f; } c; c.u = v & 0xffff0000u; return c.f; }

__device__ __forceinline__ void addv8(float* acc, uint4 v) {
  acc[0] += bf_lo(v.x); acc[1] += bf_hi(v.x);
  acc[2] += bf_lo(v.y); acc[3] += bf_hi(v.y);
  acc[4] += bf_lo(v.z); acc[5] += bf_hi(v.z);
  acc[6] += bf_lo(v.w); acc[7] += bf_hi(v.w);
}

// ---------------- merged prep + bucket histogram ----------------
__global__ void prep_hist_kernel(const int* __restrict__ dst, int* __restrict__ histG,
                                 int E, int nbuck, int nblocks,
                                 const float* __restrict__ x, ushort* __restrict__ xb,
                                 const float* __restrict__ W1, ushort* __restrict__ Wt1,
                                 const float* __restrict__ W2, ushort* __restrict__ Wt2,
                                 const float* __restrict__ W3, ushort* __restrict__ W3t,
                                 ushort* __restrict__ zbN, ushort* __restrict__ ybN, int n4) {
  __shared__ int lh[512];
  int tid = threadIdx.x;
  if ((int)blockIdx.x < nblocks) {
    int blk = blockIdx.x;
    for (int i = tid; i < nbuck; i += 256) lh[i] = 0;
    __syncthreads();
    int base = blk * EPB + tid * 4;
#pragma unroll
    for (int it = 0; it < EPB / 1024; ++it) {
      int e = base + it * 1024;
      if (e + 3 < E) {
        int4 d4 = *(const int4*)(dst + e);
        atomicAdd(&lh[d4.x >> 8], 1);
        atomicAdd(&lh[d4.y >> 8], 1);
        atomicAdd(&lh[d4.z >> 8], 1);
        atomicAdd(&lh[d4.w >> 8], 1);
      } else {
#pragma unroll
        for (int q = 0; q < 4; ++q) {
          int ee = e + q;
          if (ee < E) atomicAdd(&lh[dst[ee] >> 8], 1);
        }
      }
    }
    __syncthreads();
    for (int i = tid; i < nbuck; i += 256) histG[(size_t)i * nblocks + blk] = lh[i];
    return;
  }
  int i = ((int)blockIdx.x - nblocks) * 256 + tid;
  if (i < n4) {
    float4 v = ((const float4*)x)[i];
    ushort4 o; o.x = f2bf(v.x); o.y = f2bf(v.y); o.z = f2bf(v.z); o.w = f2bf(v.w);
    ((ushort4*)xb)[i] = o;
    return;
  }
  int j = i - n4;
  if (j < DF * DF) {
    int nr = j >> 7, k = j & 127;
    Wt1[j] = f2bf(W1[(size_t)k * DF + nr]);
    return;
  }
  j -= DF * DF;
  if (j < DF * DF) {
    int nr = j >> 7, k = j & 127;
    Wt2[j] = f2bf(W2[(size_t)k * DF + nr]);
    return;
  }
  j -= DF * DF;
  if (j < 16 * DF) {
    int nr = j >> 7, k = j & 127;
    W3t[j] = (nr < 10) ? f2bf(W3[(size_t)k * 10 + nr]) : (ushort)0;
    return;
  }
  j -= 16 * DF;
  if (j < 16) { ((uint4*)zbN)[j] = (uint4){0, 0, 0, 0}; return; }
  j -= 16;
  if (j < 16) { ((uint4*)ybN)[j] = (uint4){0, 0, 0, 0}; }
}

// ---------------- scan over per-(bucket,block) histogram ----------------
__global__ void scan1_kernel(const int* __restrict__ cnt, int* __restrict__ excl,
                             int* __restrict__ bsums, int n) {
  __shared__ int wsum[4];
  int t = threadIdx.x;
  int base = blockIdx.x * 1024 + t * 4;
  int v[4]; int s = 0;
#pragma unroll
  for (int i = 0; i < 4; i++) { int d = (base + i < n) ? cnt[base + i] : 0; v[i] = s; s += d; }
  int lane = t & 63, w = t >> 6;
  int sc = s;
#pragma unroll
  for (int off = 1; off < 64; off <<= 1) { int o = __shfl_up(sc, off); if (lane >= off) sc += o; }
  if (lane == 63) wsum[w] = sc;
  __syncthreads();
  int woff = 0;
  for (int i = 0; i < w; i++) woff += wsum[i];
  int toff = woff + (sc - s);
#pragma unroll
  for (int i = 0; i < 4; i++) if (base + i < n) excl[base + i] = toff + v[i];
  if (t == 255) bsums[blockIdx.x] = woff + sc;
}

// local exclusive scan of bsums[0..nb) into sbs (nb <= 512), 256 threads
__device__ __forceinline__ void scan_bsums_lds(const int* __restrict__ bsums, int nb,
                                               int* sbs, int* wsum) {
  int t = threadIdx.x;
  int v0 = (2 * t < nb) ? bsums[2 * t] : 0;
  int v1 = (2 * t + 1 < nb) ? bsums[2 * t + 1] : 0;
  int s = v0 + v1;
  int lane = t & 63, w = t >> 6;
  int sc = s;
#pragma unroll
  for (int off = 1; off < 64; off <<= 1) { int o = __shfl_up(sc, off); if (lane >= off) sc += o; }
  if (lane == 63) wsum[w] = sc;
  __syncthreads();
  int woff = 0;
  for (int i = 0; i < w; i++) woff += wsum[i];
  int excl = woff + sc - s;
  sbs[2 * t] = excl;
  sbs[2 * t + 1] = excl + v0;
  __syncthreads();
}

// ---------------- shared GEMM tile body: out = A @ Ws (bf16, no bias) ----------------
__device__ __forceinline__ void gemm_tiles(const ushort* __restrict__ A,
                                           const ushort* __restrict__ Ws,
                                           ushort* __restrict__ out, int n, int ntiles,
                                           int tile0, int tstride, int tid) {
  int lane = tid & 63, w = tid >> 6;
  int wr = (w >> 1) * 32, wc = (w & 1) * 64;
  int r16 = lane & 15, g8 = (lane >> 4) * 8;
  for (int tile = tile0; tile < ntiles; tile += tstride) {
    int node0 = tile * 64;
    int ra = node0 + wr + r16;      if (ra >= n) ra = n - 1;
    int rb = node0 + wr + 16 + r16; if (rb >= n) rb = n - 1;
    const ushort* pa = A + (size_t)ra * DF + g8;
    const ushort* pb = A + (size_t)rb * DF + g8;

    f32x4 acc[2][4];
#pragma unroll
    for (int i = 0; i < 2; i++)
#pragma unroll
      for (int j = 0; j < 4; j++) acc[i][j] = (f32x4){0.f, 0.f, 0.f, 0.f};

#pragma unroll
    for (int ks = 0; ks < 4; ++ks) {
      bf16x8 a0 = *(const bf16x8*)(pa + ks * 32);
      bf16x8 a1 = *(const bf16x8*)(pb + ks * 32);
      int k0 = ks * 32 + g8;
#pragma unroll
      for (int j = 0; j < 4; j++) {
        bf16x8 b = *(const bf16x8*)&Ws[(wc + j * 16 + r16) * AST + k0];
        acc[0][j] = __builtin_amdgcn_mfma_f32_16x16x32_bf16(a0, b, acc[0][j], 0, 0, 0);
        acc[1][j] = __builtin_amdgcn_mfma_f32_16x16x32_bf16(a1, b, acc[1][j], 0, 0, 0);
      }
    }

#pragma unroll
    for (int mi = 0; mi < 2; mi++) {
#pragma unroll
      for (int j = 0; j < 4; j++) {
        int col = wc + j * 16 + r16;
        int rowb = wr + mi * 16 + (lane >> 4) * 4;
#pragma unroll
        for (int q = 0; q < 4; q++) {
          int node = node0 + rowb + q;
          if (node < n) out[(size_t)node * DF + col] = f2bf(acc[mi][j][q]);
        }
      }
    }
  }
}

// ---------------- standalone persistent GEMM: zb = h1 @ W2 ----------------
__global__ __launch_bounds__(256) void gemm_plain_kernel(
    const ushort* __restrict__ A, const ushort* __restrict__ Wt,
    ushort* __restrict__ out, int n, int ntiles) {
  __shared__ ushort Ws[128 * AST];
  int t = threadIdx.x;
  for (int i = t; i < 128 * 16; i += 256) {
    int r = i >> 4, c = i & 15;
    uint4 v = ((const uint4*)(Wt + r * DF))[c];
    *(uint4*)&Ws[r * AST + c * 8] = v;
  }
  __syncthreads();
  gemm_tiles(A, Ws, out, n, ntiles, blockIdx.x, gridDim.x, t);
}

// ---------------- role-split: bucket_scatter (blocks < nblocks) || gemm_y = xb @ W1 ----------
__global__ __launch_bounds__(256) void scatter_gemm_kernel(
    const int* __restrict__ src, const int* __restrict__ dst,
    const int* __restrict__ histE, const int* __restrict__ bsums, int nb,
    uint* __restrict__ eb, int E, int nbuck, int nblocks,
    const ushort* __restrict__ xb, const ushort* __restrict__ Wt1,
    ushort* __restrict__ yb, int n, int ntiles) {
  __shared__ __align__(16) ushort Ws[128 * AST];   // gemm role; scatter overlays cursors here
  int tid = threadIdx.x;
  if ((int)blockIdx.x < nblocks) {
    int* lc   = (int*)Ws;         // 512 ints
    int* sbs  = lc + 512;         // 512 ints
    int* wsum = sbs + 512;        // 4 ints (fits well inside 34.8KB)
    int blk = blockIdx.x;
    scan_bsums_lds(bsums, nb, sbs, wsum);
    for (int i = tid; i < nbuck; i += 256) {
      int idx = i * nblocks + blk;
      lc[i] = histE[idx] + sbs[idx >> 10];
    }
    __syncthreads();
    int base = blk * EPB + tid * 4;
#pragma unroll
    for (int it = 0; it < EPB / 1024; ++it) {
      int e = base + it * 1024;
      if (e + 3 < E) {
        int4 s4 = *(const int4*)(src + e);
        int4 d4 = *(const int4*)(dst + e);
        int p0 = atomicAdd(&lc[d4.x >> 8], 1);
        eb[p0] = (uint)s4.x | ((uint)(d4.x & 255) << 24);
        int p1 = atomicAdd(&lc[d4.y >> 8], 1);
        eb[p1] = (uint)s4.y | ((uint)(d4.y & 255) << 24);
        int p2 = atomicAdd(&lc[d4.z >> 8], 1);
        eb[p2] = (uint)s4.z | ((uint)(d4.z & 255) << 24);
        int p3 = atomicAdd(&lc[d4.w >> 8], 1);
        eb[p3] = (uint)s4.w | ((uint)(d4.w & 255) << 24);
      } else {
#pragma unroll
        for (int q = 0; q < 4; ++q) {
          int ee = e + q;
          if (ee < E) {
            int d = dst[ee];
            int pos = atomicAdd(&lc[d >> 8], 1);
            eb[pos] = (uint)src[ee] | ((uint)(d & 255) << 24);
          }
        }
      }
    }
    return;
  }
  // gemm role
  for (int i = tid; i < 128 * 16; i += 256) {
    int r = i >> 4, c = i & 15;
    uint4 v = ((const uint4*)(Wt1 + r * DF))[c];
    *(uint4*)&Ws[r * AST + c * 8] = v;
  }
  __syncthreads();
  gemm_tiles(xb, Ws, yb, n, ntiles, (int)blockIdx.x - nblocks, (int)gridDim.x - nblocks, tid);
}

// ---------------- one block per bucket: counting sort, emit rowptr + csr ----------------
__global__ void bucket_sort_kernel(const uint* __restrict__ eb,
                                   const int* __restrict__ histE, const int* __restrict__ bsums,
                                   int nb, int* __restrict__ rowptr, int* __restrict__ csr,
                                   int N, int E, int nbuck, int nblocks) {
  __shared__ int cnt[256];
  __shared__ int cursor[256];
  __shared__ int sbs[512];
  __shared__ int wsum[4];
  int tid = threadIdx.x, b = blockIdx.x;
  scan_bsums_lds(bsums, nb, sbs, wsum);
  int idx = b * nblocks;
  int beg = histE[idx] + sbs[idx >> 10];
  int end = E;
  if (b + 1 < nbuck) { int i2 = (b + 1) * nblocks; end = histE[i2] + sbs[i2 >> 10]; }
  cnt[tid] = 0;
  __syncthreads();
  for (int e = beg + tid; e < end; e += 256)
    atomicAdd(&cnt[eb[e] >> 24], 1);
  __syncthreads();
  int v = cnt[tid];
  int lane = tid & 63, w = tid >> 6;
  int sc = v;
#pragma unroll
  for (int off = 1; off < 64; off <<= 1) { int o = __shfl_up(sc, off); if (lane >= off) sc += o; }
  if (lane == 63) wsum[w] = sc;
  __syncthreads();
  int woff = 0;
  for (int i = 0; i < w; i++) woff += wsum[i];
  int excl = woff + sc - v;
  int node = (b << 8) + tid;
  if (node <= N) rowptr[node] = beg + excl;
  cursor[tid] = beg + excl;
  __syncthreads();
  for (int e = beg + tid; e < end; e += 256) {
    uint vv = eb[e];
    int pos = atomicAdd(&cursor[vv >> 24], 1);
    csr[pos] = (int)(vv & 0x00FFFFFFu);
  }
}

// ---------------- gather-mean core: acc[8] per 16-lane group ----------------
__device__ __forceinline__ void gather_mean(const ushort* __restrict__ src,
                                            const int* __restrict__ rowptr,
                                            const int* __restrict__ csr,
                                            int node, int n, uint c16, float* acc) {
  int beg = rowptr[node], end = rowptr[node + 1];
  const char* xbase = (const char*)src;
#pragma unroll
  for (int i = 0; i < 8; i++) acc[i] = 0.f;
  int deg = end - beg;
  if (deg > 0) {
#pragma unroll 1
    for (int e = beg; e < end; e += 4) {
      int e1 = e + 1, e2 = e + 2, e3 = e + 3;
      uint r0 = (uint)csr[e];
      uint r1 = (e1 < end) ? (uint)csr[e1] : (uint)n;
      uint r2 = (e2 < end) ? (uint)csr[e2] : (uint)n;
      uint r3 = (e3 < end) ? (uint)csr[e3] : (uint)n;
      uint4 v0 = *(const uint4*)(xbase + (r0 * 256u + c16));
      uint4 v1 = *(const uint4*)(xbase + (r1 * 256u + c16));
      uint4 v2 = *(const uint4*)(xbase + (r2 * 256u + c16));
      uint4 v3 = *(const uint4*)(xbase + (r3 * 256u + c16));
      addv8(acc, v0);
      addv8(acc, v1);
      addv8(acc, v2);
      addv8(acc, v3);
    }
    float inv = 1.0f / (float)deg;
#pragma unroll
    for (int i = 0; i < 8; i++) acc[i] *= inv;
  } else {
    uint4 v = *(const uint4*)(xbase + ((uint)node * 256u + c16));
    float t[8] = {0, 0, 0, 0, 0, 0, 0, 0};
    addv8(t, v);
#pragma unroll
    for (int i = 0; i < 8; i++) acc[i] = t[i];
  }
}

// ---------------- agg1: h1 = tanh(mean_or_self(yb) + b1) ----------------
__global__ __launch_bounds__(256) void agg_bias_tanh_kernel(
    const ushort* __restrict__ yb, const int* __restrict__ rowptr,
    const int* __restrict__ csr, const float* __restrict__ bias,
    ushort* __restrict__ h1, int n) {
  int tid = threadIdx.x;
  int node = (blockIdx.x * 256 + tid) >> 4;
  if (node >= n) return;
  uint c16 = (uint)(tid & 15) * 16u;
  float acc[8];
  gather_mean(yb, rowptr, csr, node, n, c16, acc);
  int d8 = (tid & 15) * 8;
  float4 bA = *(const float4*)(bias + d8);
  float4 bB = *(const float4*)(bias + d8 + 4);
  float h0 = tanhf(acc[0] + bA.x), hh1 = tanhf(acc[1] + bA.y);
  float h2 = tanhf(acc[2] + bA.z), h3 = tanhf(acc[3] + bA.w);
  float h4 = tanhf(acc[4] + bB.x), h5 = tanhf(acc[5] + bB.y);
  float h6 = tanhf(acc[6] + bB.z), h7 = tanhf(acc[7] + bB.w);
  uint4 r;
  r.x = (uint)f2bf(h0) | ((uint)f2bf(hh1) << 16);
  r.y = (uint)f2bf(h2) | ((uint)f2bf(h3) << 16);
  r.z = (uint)f2bf(h4) | ((uint)f2bf(h5) << 16);
  r.w = (uint)f2bf(h6) | ((uint)f2bf(h7) << 16);
  *(uint4*)((char*)h1 + ((uint)node * 256u + c16)) = r;
}

// ---------------- agg2 + MFMA head: logits = tanh(mean_or_self(zb)+b2) @ W3 + b3 ----------
// Block = exactly 16 nodes. Each 16-lane group computes its node's h (bf16) into
// Hs[16][AST]; wave 0 then does 4 MFMAs vs W3t (bf16, 16x128) and writes logits.
__global__ __launch_bounds__(256) void agg_head_kernel(
    const ushort* __restrict__ zb, const int* __restrict__ rowptr,
    const int* __restrict__ csr, const float* __restrict__ b2,
    const ushort* __restrict__ W3t, const float* __restrict__ b3,
    float* __restrict__ out, int n) {
  __shared__ __align__(16) ushort Hs[16 * AST];
  __shared__ __align__(16) ushort W3s[16 * AST];
  int tid = threadIdx.x;
  {
    int r = tid >> 4, c = tid & 15;
    uint4 v = ((const uint4*)(W3t + r * DF))[c];
    *(uint4*)&W3s[r * AST + c * 8] = v;
  }
  int node = (blockIdx.x * 256 + tid) >> 4;
  int node_ib = tid >> 4;
  uint c16 = (uint)(tid & 15) * 16u;
  bool active = node < n;
  uint4 hr = (uint4){0, 0, 0, 0};
  if (active) {
    float acc[8];
    gather_mean(zb, rowptr, csr, node, n, c16, acc);
    int d8 = (tid & 15) * 8;
    float4 bA = *(const float4*)(b2 + d8);
    float4 bB = *(const float4*)(b2 + d8 + 4);
    float h0 = tanhf(acc[0] + bA.x), h1 = tanhf(acc[1] + bA.y);
    float h2 = tanhf(acc[2] + bA.z), h3 = tanhf(acc[3] + bA.w);
    float h4 = tanhf(acc[4] + bB.x), h5 = tanhf(acc[5] + bB.y);
    float h6 = tanhf(acc[6] + bB.z), h7 = tanhf(acc[7] + bB.w);
    hr.x = (uint)f2bf(h0) | ((uint)f2bf(h1) << 16);
    hr.y = (uint)f2bf(h2) | ((uint)f2bf(h3) << 16);
    hr.z = (uint)f2bf(h4) | ((uint)f2bf(h5) << 16);
    hr.w = (uint)f2bf(h6) | ((uint)f2bf(h7) << 16);
  }
  *(uint4*)&Hs[node_ib * AST + (tid & 15) * 8] = hr;
  __syncthreads();

  if (tid < 64) {
    int l16 = tid & 15, g8 = (tid >> 4) * 8;
    f32x4 acc = (f32x4){0.f, 0.f, 0.f, 0.f};
#pragma unroll
    for (int ks = 0; ks < 4; ++ks) {
      bf16x8 a = *(const bf16x8*)&Hs[l16 * AST + ks * 32 + g8];
      bf16x8 b = *(const bf16x8*)&W3s[l16 * AST + ks * 32 + g8];
      acc = __builtin_amdgcn_mfma_f32_16x16x32_bf16(a, b, acc, 0, 0, 0);
    }
    // C/D: col = lane&15 (class), row = (lane>>4)*4 + q (node_ib)
    if (l16 < 10) {
      float bv = b3[l16];
#pragma unroll
      for (int q = 0; q < 4; ++q) {
        int nib = (tid >> 4) * 4 + q;
        int nd = blockIdx.x * 16 + nib;
        if (nd < n) out[(size_t)nd * 10 + l16] = acc[q] + bv;
      }
    }
  }
}

extern "C" void kernel_launch(void* const* d_in, const int* in_sizes, int n_in,
                              void* d_out, int out_size, void* d_ws, size_t ws_size,
                              hipStream_t stream) {
  const float* x    = (const float*)d_in[0];
  const int*   esrc = (const int*)d_in[1];
  const int*   edst = (const int*)d_in[2];
  const float* W1   = (const float*)d_in[3];
  const float* b1   = (const float*)d_in[4];
  const float* W2   = (const float*)d_in[5];
  const float* b2   = (const float*)d_in[6];
  const float* W3   = (const float*)d_in[7];
  const float* b3   = (const float*)d_in[8];
  float* out = (float*)d_out;

  const int N = in_sizes[0] / DF;   // 100000
  const int E = in_sizes[1];        // 1600000

  const int nbuck   = (N + 255) >> 8;            // 391
  const int nblocks = (E + EPB - 1) / EPB;       // 391
  const int M = nbuck * nblocks;                 // ~153K

  // workspace layout
  char* ws = (char*)d_ws;
  int*  rowptr = (int*)ws;               // N+1
  int*  csr    = rowptr + (N + 1);       // E
  int*  histG  = csr + E;                // M
  int*  histE  = histG + M;              // M
  int*  bsums2 = histE + M;              // 1024
  uint* eb     = (uint*)(bsums2 + 1024); // E
  size_t off = (size_t)((char*)(eb + E) - ws);
  off = (off + 255) & ~(size_t)255;
  ushort* xb  = (ushort*)(ws + off);     off += (size_t)(N + 1) * DF * 2; off = (off + 255) & ~(size_t)255;  // doubles as zb
  ushort* Wt1 = (ushort*)(ws + off);     off += (size_t)DF * DF * 2;
  ushort* Wt2 = (ushort*)(ws + off);     off += (size_t)DF * DF * 2;
  ushort* W3t = (ushort*)(ws + off);     off += (size_t)16 * DF * 2; off = (off + 255) & ~(size_t)255;
  ushort* yb  = (ushort*)(ws + off);     off += (size_t)(N + 1) * DF * 2; off = (off + 255) & ~(size_t)255;
  ushort* h1  = (ushort*)(ws + off);
  ushort* zb  = xb;   // xb is dead after gemm_y; reuse (row N zeroed in prep)

  // merged prep + hist
  int n4 = N * DF / 4;
  int prep_total = n4 + 2 * DF * DF + 16 * DF + 32;
  int prep_blocks = (prep_total + 255) / 256;
  prep_hist_kernel<<<nblocks + prep_blocks, 256, 0, stream>>>(
      edst, histG, E, nbuck, nblocks,
      x, xb, W1, Wt1, W2, Wt2, W3, W3t,
      xb + (size_t)N * DF, yb + (size_t)N * DF, n4);

  int nb_m = (M + 1023) / 1024;
  int ntiles = (N + 63) / 64;

  scan1_kernel<<<nb_m, 256, 0, stream>>>(histG, histE, bsums2, M);

  // bucket_scatter || gemm_y = xb @ W1
  scatter_gemm_kernel<<<nblocks + 512, 256, 0, stream>>>(
      esrc, edst, histE, bsums2, nb_m, eb, E, nbuck, nblocks,
      xb, Wt1, yb, N, ntiles);

  bucket_sort_kernel<<<nbuck, 256, 0, stream>>>(eb, histE, bsums2, nb_m, rowptr, csr, N, E, nbuck, nblocks);

  int agg_blocks = (N + 15) / 16;

  // layer 1: h1 = tanh(mean_or_self(yb) + b1)
  agg_bias_tanh_kernel<<<agg_blocks, 256, 0, stream>>>(yb, rowptr, csr, b1, h1, N);
  // layer 2 GEMM: zb = h1 @ W2
  gemm_plain_kernel<<<512, 256, 0, stream>>>(h1, Wt2, zb, N, ntiles);
  // layer 2 aggregate + MFMA head
  agg_head_kernel<<<agg_blocks, 256, 0, stream>>>(zb, rowptr, csr, b2, W3t, b3, out, N);
}

// Round 15
// 187.490 us; speedup vs baseline: 1.2519x; 1.0013x over previous
//
#include <hip/hip_runtime.h>

#define DF 128
#define AST 136   // padded LDS row stride (bf16 elems)
#define EPB 4096  // edges per block in bucket passes

typedef float f32x4 __attribute__((ext_vector_type(4)));
typedef short bf16x8 __attribute__((ext_vector_type(8)));

__device__ __forceinline__ ushort f2bf(float f) {
  union { float f; uint u; } c; c.f = f;
  uint u = c.u;
  uint r = (u + 0x7fffu + ((u >> 16) & 1u)) >> 16;   // RNE
  return (ushort)r;
}
__device__ __forceinline__ float bf_lo(uint v) { union { uint u; float f; } c; c.u = v << 16; return c.f; }
__device__ __forceinline__ float bf_hi(uint v) { union { uint u; float f; } c; c.u = v & 0xffff0000u; return c.f; }

__device__ __forceinline__ void addv8(float* acc, uint4 v) {
  acc[0] += bf_lo(v.x); acc[1] += bf_hi(v.x);
  acc[2] += bf_lo(v.y); acc[3] += bf_hi(v.y);
  acc[4] += bf_lo(v.z); acc[5] += bf_hi(v.z);
  acc[6] += bf_lo(v.w); acc[7] += bf_hi(v.w);
}

// ---------------- merged prep + bucket histogram ----------------
__global__ void prep_hist_kernel(const int* __restrict__ dst, int* __restrict__ histG,
                                 int E, int nbuck, int nblocks,
                                 const float* __restrict__ x, ushort* __restrict__ xb,
                                 const float* __restrict__ W1, ushort* __restrict__ Wt1,
                                 const float* __restrict__ W2, ushort* __restrict__ Wt2,
                                 const float* __restrict__ W3, ushort* __restrict__ W3t,
                                 ushort* __restrict__ zbN, ushort* __restrict__ ybN, int n4) {
  __shared__ int lh[512];
  int tid = threadIdx.x;
  if ((int)blockIdx.x < nblocks) {
    int blk = blockIdx.x;
    for (int i = tid; i < nbuck; i += 256) lh[i] = 0;
    __syncthreads();
    int base = blk * EPB + tid * 4;
#pragma unroll
    for (int it = 0; it < EPB / 1024; ++it) {
      int e = base + it * 1024;
      if (e + 3 < E) {
        int4 d4 = *(const int4*)(dst + e);
        atomicAdd(&lh[d4.x >> 8], 1);
        atomicAdd(&lh[d4.y >> 8], 1);
        atomicAdd(&lh[d4.z >> 8], 1);
        atomicAdd(&lh[d4.w >> 8], 1);
      } else {
#pragma unroll
        for (int q = 0; q < 4; ++q) {
          int ee = e + q;
          if (ee < E) atomicAdd(&lh[dst[ee] >> 8], 1);
        }
      }
    }
    __syncthreads();
    for (int i = tid; i < nbuck; i += 256) histG[(size_t)i * nblocks + blk] = lh[i];
    return;
  }
  int i = ((int)blockIdx.x - nblocks) * 256 + tid;
  if (i < n4) {
    float4 v = ((const float4*)x)[i];
    ushort4 o; o.x = f2bf(v.x); o.y = f2bf(v.y); o.z = f2bf(v.z); o.w = f2bf(v.w);
    ((ushort4*)xb)[i] = o;
    return;
  }
  int j = i - n4;
  if (j < DF * DF) {
    int nr = j >> 7, k = j & 127;
    Wt1[j] = f2bf(W1[(size_t)k * DF + nr]);
    return;
  }
  j -= DF * DF;
  if (j < DF * DF) {
    int nr = j >> 7, k = j & 127;
    Wt2[j] = f2bf(W2[(size_t)k * DF + nr]);
    return;
  }
  j -= DF * DF;
  if (j < 16 * DF) {
    int nr = j >> 7, k = j & 127;
    W3t[j] = (nr < 10) ? f2bf(W3[(size_t)k * 10 + nr]) : (ushort)0;
    return;
  }
  j -= 16 * DF;
  if (j < 16) { ((uint4*)zbN)[j] = (uint4){0, 0, 0, 0}; return; }
  j -= 16;
  if (j < 16) { ((uint4*)ybN)[j] = (uint4){0, 0, 0, 0}; }
}

// ---------------- scan over per-(bucket,block) histogram ----------------
__global__ void scan1_kernel(const int* __restrict__ cnt, int* __restrict__ excl,
                             int* __restrict__ bsums, int n) {
  __shared__ int wsum[4];
  int t = threadIdx.x;
  int base = blockIdx.x * 1024 + t * 4;
  int v[4]; int s = 0;
#pragma unroll
  for (int i = 0; i < 4; i++) { int d = (base + i < n) ? cnt[base + i] : 0; v[i] = s; s += d; }
  int lane = t & 63, w = t >> 6;
  int sc = s;
#pragma unroll
  for (int off = 1; off < 64; off <<= 1) { int o = __shfl_up(sc, off); if (lane >= off) sc += o; }
  if (lane == 63) wsum[w] = sc;
  __syncthreads();
  int woff = 0;
  for (int i = 0; i < w; i++) woff += wsum[i];
  int toff = woff + (sc - s);
#pragma unroll
  for (int i = 0; i < 4; i++) if (base + i < n) excl[base + i] = toff + v[i];
  if (t == 255) bsums[blockIdx.x] = woff + sc;
}

// local exclusive scan of bsums[0..nb) into sbs (nb <= 512), 256 threads
__device__ __forceinline__ void scan_bsums_lds(const int* __restrict__ bsums, int nb,
                                               int* sbs, int* wsum) {
  int t = threadIdx.x;
  int v0 = (2 * t < nb) ? bsums[2 * t] : 0;
  int v1 = (2 * t + 1 < nb) ? bsums[2 * t + 1] : 0;
  int s = v0 + v1;
  int lane = t & 63, w = t >> 6;
  int sc = s;
#pragma unroll
  for (int off = 1; off < 64; off <<= 1) { int o = __shfl_up(sc, off); if (lane >= off) sc += o; }
  if (lane == 63) wsum[w] = sc;
  __syncthreads();
  int woff = 0;
  for (int i = 0; i < w; i++) woff += wsum[i];
  int excl = woff + sc - s;
  sbs[2 * t] = excl;
  sbs[2 * t + 1] = excl + v0;
  __syncthreads();
}

// ---------------- shared GEMM tile body: out = A @ Ws (bf16, no bias) ----------------
__device__ __forceinline__ void gemm_tiles(const ushort* __restrict__ A,
                                           const ushort* __restrict__ Ws,
                                           ushort* __restrict__ out, int n, int ntiles,
                                           int tile0, int tstride, int tid) {
  int lane = tid & 63, w = tid >> 6;
  int wr = (w >> 1) * 32, wc = (w & 1) * 64;
  int r16 = lane & 15, g8 = (lane >> 4) * 8;
  for (int tile = tile0; tile < ntiles; tile += tstride) {
    int node0 = tile * 64;
    int ra = node0 + wr + r16;      if (ra >= n) ra = n - 1;
    int rb = node0 + wr + 16 + r16; if (rb >= n) rb = n - 1;
    const ushort* pa = A + (size_t)ra * DF + g8;
    const ushort* pb = A + (size_t)rb * DF + g8;

    f32x4 acc[2][4];
#pragma unroll
    for (int i = 0; i < 2; i++)
#pragma unroll
      for (int j = 0; j < 4; j++) acc[i][j] = (f32x4){0.f, 0.f, 0.f, 0.f};

#pragma unroll
    for (int ks = 0; ks < 4; ++ks) {
      bf16x8 a0 = *(const bf16x8*)(pa + ks * 32);
      bf16x8 a1 = *(const bf16x8*)(pb + ks * 32);
      int k0 = ks * 32 + g8;
#pragma unroll
      for (int j = 0; j < 4; j++) {
        bf16x8 b = *(const bf16x8*)&Ws[(wc + j * 16 + r16) * AST + k0];
        acc[0][j] = __builtin_amdgcn_mfma_f32_16x16x32_bf16(a0, b, acc[0][j], 0, 0, 0);
        acc[1][j] = __builtin_amdgcn_mfma_f32_16x16x32_bf16(a1, b, acc[1][j], 0, 0, 0);
      }
    }

#pragma unroll
    for (int mi = 0; mi < 2; mi++) {
#pragma unroll
      for (int j = 0; j < 4; j++) {
        int col = wc + j * 16 + r16;
        int rowb = wr + mi * 16 + (lane >> 4) * 4;
#pragma unroll
        for (int q = 0; q < 4; q++) {
          int node = node0 + rowb + q;
          if (node < n) out[(size_t)node * DF + col] = f2bf(acc[mi][j][q]);
        }
      }
    }
  }
}

// ---------------- standalone persistent GEMM: zb = h1 @ W2 ----------------
__global__ __launch_bounds__(256) void gemm_plain_kernel(
    const ushort* __restrict__ A, const ushort* __restrict__ Wt,
    ushort* __restrict__ out, int n, int ntiles) {
  __shared__ ushort Ws[128 * AST];
  int t = threadIdx.x;
  for (int i = t; i < 128 * 16; i += 256) {
    int r = i >> 4, c = i & 15;
    uint4 v = ((const uint4*)(Wt + r * DF))[c];
    *(uint4*)&Ws[r * AST + c * 8] = v;
  }
  __syncthreads();
  gemm_tiles(A, Ws, out, n, ntiles, blockIdx.x, gridDim.x, t);
}

// ---------------- role-split: bucket_scatter (blocks < nblocks) || gemm_y = xb @ W1 ----------
__global__ __launch_bounds__(256) void scatter_gemm_kernel(
    const int* __restrict__ src, const int* __restrict__ dst,
    const int* __restrict__ histE, const int* __restrict__ bsums, int nb,
    uint* __restrict__ eb, int E, int nbuck, int nblocks,
    const ushort* __restrict__ xb, const ushort* __restrict__ Wt1,
    ushort* __restrict__ yb, int n, int ntiles) {
  __shared__ __align__(16) ushort Ws[128 * AST];   // gemm role; scatter overlays cursors here
  int tid = threadIdx.x;
  if ((int)blockIdx.x < nblocks) {
    int* lc   = (int*)Ws;         // 512 ints
    int* sbs  = lc + 512;         // 512 ints
    int* wsum = sbs + 512;        // 4 ints (fits well inside 34.8KB)
    int blk = blockIdx.x;
    scan_bsums_lds(bsums, nb, sbs, wsum);
    for (int i = tid; i < nbuck; i += 256) {
      int idx = i * nblocks + blk;
      lc[i] = histE[idx] + sbs[idx >> 10];
    }
    __syncthreads();
    int base = blk * EPB + tid * 4;
#pragma unroll
    for (int it = 0; it < EPB / 1024; ++it) {
      int e = base + it * 1024;
      if (e + 3 < E) {
        int4 s4 = *(const int4*)(src + e);
        int4 d4 = *(const int4*)(dst + e);
        int p0 = atomicAdd(&lc[d4.x >> 8], 1);
        eb[p0] = (uint)s4.x | ((uint)(d4.x & 255) << 24);
        int p1 = atomicAdd(&lc[d4.y >> 8], 1);
        eb[p1] = (uint)s4.y | ((uint)(d4.y & 255) << 24);
        int p2 = atomicAdd(&lc[d4.z >> 8], 1);
        eb[p2] = (uint)s4.z | ((uint)(d4.z & 255) << 24);
        int p3 = atomicAdd(&lc[d4.w >> 8], 1);
        eb[p3] = (uint)s4.w | ((uint)(d4.w & 255) << 24);
      } else {
#pragma unroll
        for (int q = 0; q < 4; ++q) {
          int ee = e + q;
          if (ee < E) {
            int d = dst[ee];
            int pos = atomicAdd(&lc[d >> 8], 1);
            eb[pos] = (uint)src[ee] | ((uint)(d & 255) << 24);
          }
        }
      }
    }
    return;
  }
  // gemm role
  for (int i = tid; i < 128 * 16; i += 256) {
    int r = i >> 4, c = i & 15;
    uint4 v = ((const uint4*)(Wt1 + r * DF))[c];
    *(uint4*)&Ws[r * AST + c * 8] = v;
  }
  __syncthreads();
  gemm_tiles(xb, Ws, yb, n, ntiles, (int)blockIdx.x - nblocks, (int)gridDim.x - nblocks, tid);
}

// ---------------- one block per bucket: counting sort, emit rowptr + csr ----------------
__global__ void bucket_sort_kernel(const uint* __restrict__ eb,
                                   const int* __restrict__ histE, const int* __restrict__ bsums,
                                   int nb, int* __restrict__ rowptr, int* __restrict__ csr,
                                   int N, int E, int nbuck, int nblocks) {
  __shared__ int cnt[256];
  __shared__ int cursor[256];
  __shared__ int sbs[512];
  __shared__ int wsum[4];
  int tid = threadIdx.x, b = blockIdx.x;
  scan_bsums_lds(bsums, nb, sbs, wsum);
  int idx = b * nblocks;
  int beg = histE[idx] + sbs[idx >> 10];
  int end = E;
  if (b + 1 < nbuck) { int i2 = (b + 1) * nblocks; end = histE[i2] + sbs[i2 >> 10]; }
  cnt[tid] = 0;
  __syncthreads();
  for (int e = beg + tid; e < end; e += 256)
    atomicAdd(&cnt[eb[e] >> 24], 1);
  __syncthreads();
  int v = cnt[tid];
  int lane = tid & 63, w = tid >> 6;
  int sc = v;
#pragma unroll
  for (int off = 1; off < 64; off <<= 1) { int o = __shfl_up(sc, off); if (lane >= off) sc += o; }
  if (lane == 63) wsum[w] = sc;
  __syncthreads();
  int woff = 0;
  for (int i = 0; i < w; i++) woff += wsum[i];
  int excl = woff + sc - v;
  int node = (b << 8) + tid;
  if (node <= N) rowptr[node] = beg + excl;
  cursor[tid] = beg + excl;
  __syncthreads();
  for (int e = beg + tid; e < end; e += 256) {
    uint vv = eb[e];
    int pos = atomicAdd(&cursor[vv >> 24], 1);
    csr[pos] = (int)(vv & 0x00FFFFFFu);
  }
}

// ---------------- gather-mean core: acc[8] per 16-lane group ----------------
__device__ __forceinline__ void gather_mean(const ushort* __restrict__ src,
                                            const int* __restrict__ rowptr,
                                            const int* __restrict__ csr,
                                            int node, int n, uint c16, float* acc) {
  int beg = rowptr[node], end = rowptr[node + 1];
  const char* xbase = (const char*)src;
#pragma unroll
  for (int i = 0; i < 8; i++) acc[i] = 0.f;
  int deg = end - beg;
  if (deg > 0) {
#pragma unroll 1
    for (int e = beg; e < end; e += 4) {
      int e1 = e + 1, e2 = e + 2, e3 = e + 3;
      uint r0 = (uint)csr[e];
      uint r1 = (e1 < end) ? (uint)csr[e1] : (uint)n;
      uint r2 = (e2 < end) ? (uint)csr[e2] : (uint)n;
      uint r3 = (e3 < end) ? (uint)csr[e3] : (uint)n;
      uint4 v0 = *(const uint4*)(xbase + (r0 * 256u + c16));
      uint4 v1 = *(const uint4*)(xbase + (r1 * 256u + c16));
      uint4 v2 = *(const uint4*)(xbase + (r2 * 256u + c16));
      uint4 v3 = *(const uint4*)(xbase + (r3 * 256u + c16));
      addv8(acc, v0);
      addv8(acc, v1);
      addv8(acc, v2);
      addv8(acc, v3);
    }
    float inv = 1.0f / (float)deg;
#pragma unroll
    for (int i = 0; i < 8; i++) acc[i] *= inv;
  } else {
    uint4 v = *(const uint4*)(xbase + ((uint)node * 256u + c16));
    float t[8] = {0, 0, 0, 0, 0, 0, 0, 0};
    addv8(t, v);
#pragma unroll
    for (int i = 0; i < 8; i++) acc[i] = t[i];
  }
}

// ---------------- agg1: h1 = tanh(mean_or_self(yb) + b1) ----------------
__global__ __launch_bounds__(256) void agg_bias_tanh_kernel(
    const ushort* __restrict__ yb, const int* __restrict__ rowptr,
    const int* __restrict__ csr, const float* __restrict__ bias,
    ushort* __restrict__ h1, int n) {
  int tid = threadIdx.x;
  int node = (blockIdx.x * 256 + tid) >> 4;
  if (node >= n) return;
  uint c16 = (uint)(tid & 15) * 16u;
  float acc[8];
  gather_mean(yb, rowptr, csr, node, n, c16, acc);
  int d8 = (tid & 15) * 8;
  float4 bA = *(const float4*)(bias + d8);
  float4 bB = *(const float4*)(bias + d8 + 4);
  float h0 = tanhf(acc[0] + bA.x), hh1 = tanhf(acc[1] + bA.y);
  float h2 = tanhf(acc[2] + bA.z), h3 = tanhf(acc[3] + bA.w);
  float h4 = tanhf(acc[4] + bB.x), h5 = tanhf(acc[5] + bB.y);
  float h6 = tanhf(acc[6] + bB.z), h7 = tanhf(acc[7] + bB.w);
  uint4 r;
  r.x = (uint)f2bf(h0) | ((uint)f2bf(hh1) << 16);
  r.y = (uint)f2bf(h2) | ((uint)f2bf(h3) << 16);
  r.z = (uint)f2bf(h4) | ((uint)f2bf(h5) << 16);
  r.w = (uint)f2bf(h6) | ((uint)f2bf(h7) << 16);
  *(uint4*)((char*)h1 + ((uint)node * 256u + c16)) = r;
}

// ---------------- agg2 + MFMA head: logits = tanh(mean_or_self(zb)+b2) @ W3 + b3 ----------
// Block = exactly 16 nodes. Each 16-lane group computes its node's h (bf16) into
// Hs[16][AST]; wave 0 then does 4 MFMAs vs W3t (bf16, 16x128) and writes logits.
__global__ __launch_bounds__(256) void agg_head_kernel(
    const ushort* __restrict__ zb, const int* __restrict__ rowptr,
    const int* __restrict__ csr, const float* __restrict__ b2,
    const ushort* __restrict__ W3t, const float* __restrict__ b3,
    float* __restrict__ out, int n) {
  __shared__ __align__(16) ushort Hs[16 * AST];
  __shared__ __align__(16) ushort W3s[16 * AST];
  int tid = threadIdx.x;
  {
    int r = tid >> 4, c = tid & 15;
    uint4 v = ((const uint4*)(W3t + r * DF))[c];
    *(uint4*)&W3s[r * AST + c * 8] = v;
  }
  int node = (blockIdx.x * 256 + tid) >> 4;
  int node_ib = tid >> 4;
  uint c16 = (uint)(tid & 15) * 16u;
  bool active = node < n;
  uint4 hr = (uint4){0, 0, 0, 0};
  if (active) {
    float acc[8];
    gather_mean(zb, rowptr, csr, node, n, c16, acc);
    int d8 = (tid & 15) * 8;
    float4 bA = *(const float4*)(b2 + d8);
    float4 bB = *(const float4*)(b2 + d8 + 4);
    float h0 = tanhf(acc[0] + bA.x), h1 = tanhf(acc[1] + bA.y);
    float h2 = tanhf(acc[2] + bA.z), h3 = tanhf(acc[3] + bA.w);
    float h4 = tanhf(acc[4] + bB.x), h5 = tanhf(acc[5] + bB.y);
    float h6 = tanhf(acc[6] + bB.z), h7 = tanhf(acc[7] + bB.w);
    hr.x = (uint)f2bf(h0) | ((uint)f2bf(h1) << 16);
    hr.y = (uint)f2bf(h2) | ((uint)f2bf(h3) << 16);
    hr.z = (uint)f2bf(h4) | ((uint)f2bf(h5) << 16);
    hr.w = (uint)f2bf(h6) | ((uint)f2bf(h7) << 16);
  }
  *(uint4*)&Hs[node_ib * AST + (tid & 15) * 8] = hr;
  __syncthreads();

  if (tid < 64) {
    int l16 = tid & 15, g8 = (tid >> 4) * 8;
    f32x4 acc = (f32x4){0.f, 0.f, 0.f, 0.f};
#pragma unroll
    for (int ks = 0; ks < 4; ++ks) {
      bf16x8 a = *(const bf16x8*)&Hs[l16 * AST + ks * 32 + g8];
      bf16x8 b = *(const bf16x8*)&W3s[l16 * AST + ks * 32 + g8];
      acc = __builtin_amdgcn_mfma_f32_16x16x32_bf16(a, b, acc, 0, 0, 0);
    }
    // C/D: col = lane&15 (class), row = (lane>>4)*4 + q (node_ib)
    if (l16 < 10) {
      float bv = b3[l16];
#pragma unroll
      for (int q = 0; q < 4; ++q) {
        int nib = (tid >> 4) * 4 + q;
        int nd = blockIdx.x * 16 + nib;
        if (nd < n) out[(size_t)nd * 10 + l16] = acc[q] + bv;
      }
    }
  }
}

extern "C" void kernel_launch(void* const* d_in, const int* in_sizes, int n_in,
                              void* d_out, int out_size, void* d_ws, size_t ws_size,
                              hipStream_t stream) {
  const float* x    = (const float*)d_in[0];
  const int*   esrc = (const int*)d_in[1];
  const int*   edst = (const int*)d_in[2];
  const float* W1   = (const float*)d_in[3];
  const float* b1   = (const float*)d_in[4];
  const float* W2   = (const float*)d_in[5];
  const float* b2   = (const float*)d_in[6];
  const float* W3   = (const float*)d_in[7];
  const float* b3   = (const float*)d_in[8];
  float* out = (float*)d_out;

  const int N = in_sizes[0] / DF;   // 100000
  const int E = in_sizes[1];        // 1600000

  const int nbuck   = (N + 255) >> 8;            // 391
  const int nblocks = (E + EPB - 1) / EPB;       // 391
  const int M = nbuck * nblocks;                 // ~153K

  // workspace layout
  char* ws = (char*)d_ws;
  int*  rowptr = (int*)ws;               // N+1
  int*  csr    = rowptr + (N + 1);       // E
  int*  histG  = csr + E;                // M
  int*  histE  = histG + M;              // M
  int*  bsums2 = histE + M;              // 1024
  uint* eb     = (uint*)(bsums2 + 1024); // E
  size_t off = (size_t)((char*)(eb + E) - ws);
  off = (off + 255) & ~(size_t)255;
  ushort* xb  = (ushort*)(ws + off);     off += (size_t)(N + 1) * DF * 2; off = (off + 255) & ~(size_t)255;  // doubles as zb
  ushort* Wt1 = (ushort*)(ws + off);     off += (size_t)DF * DF * 2;
  ushort* Wt2 = (ushort*)(ws + off);     off += (size_t)DF * DF * 2;
  ushort* W3t = (ushort*)(ws + off);     off += (size_t)16 * DF * 2; off = (off + 255) & ~(size_t)255;
  ushort* yb  = (ushort*)(ws + off);     off += (size_t)(N + 1) * DF * 2; off = (off + 255) & ~(size_t)255;
  ushort* h1  = (ushort*)(ws + off);
  ushort* zb  = xb;   // xb is dead after gemm_y; reuse (row N zeroed in prep)

  // merged prep + hist
  int n4 = N * DF / 4;
  int prep_total = n4 + 2 * DF * DF + 16 * DF + 32;
  int prep_blocks = (prep_total + 255) / 256;
  prep_hist_kernel<<<nblocks + prep_blocks, 256, 0, stream>>>(
      edst, histG, E, nbuck, nblocks,
      x, xb, W1, Wt1, W2, Wt2, W3, W3t,
      xb + (size_t)N * DF, yb + (size_t)N * DF, n4);

  int nb_m = (M + 1023) / 1024;
  int ntiles = (N + 63) / 64;

  scan1_kernel<<<nb_m, 256, 0, stream>>>(histG, histE, bsums2, M);

  // bucket_scatter || gemm_y = xb @ W1
  scatter_gemm_kernel<<<nblocks + 512, 256, 0, stream>>>(
      esrc, edst, histE, bsums2, nb_m, eb, E, nbuck, nblocks,
      xb, Wt1, yb, N, ntiles);

  bucket_sort_kernel<<<nbuck, 256, 0, stream>>>(eb, histE, bsums2, nb_m, rowptr, csr, N, E, nbuck, nblocks);

  int agg_blocks = (N + 15) / 16;

  // layer 1: h1 = tanh(mean_or_self(yb) + b1)
  agg_bias_tanh_kernel<<<agg_blocks, 256, 0, stream>>>(yb, rowptr, csr, b1, h1, N);
  // layer 2 GEMM: zb = h1 @ W2
  gemm_plain_kernel<<<512, 256, 0, stream>>>(h1, Wt2, zb, N, ntiles);
  // layer 2 aggregate + MFMA head
  agg_head_kernel<<<agg_blocks, 256, 0, stream>>>(zb, rowptr, csr, b2, W3t, b3, out, N);
}

// Round 16
// 182.105 us; speedup vs baseline: 1.2889x; 1.0296x over previous
//
#include <hip/hip_runtime.h>

#define DF 128
#define AST 136   // padded LDS row stride (bf16 elems)
#define EPB 4096  // edges per block in bucket passes

typedef float f32x4 __attribute__((ext_vector_type(4)));
typedef short bf16x8 __attribute__((ext_vector_type(8)));

__device__ __forceinline__ ushort f2bf(float f) {
  union { float f; uint u; } c; c.f = f;
  uint u = c.u;
  uint r = (u + 0x7fffu + ((u >> 16) & 1u)) >> 16;   // RNE
  return (ushort)r;
}
__device__ __forceinline__ float bf_lo(uint v) { union { uint u; float f; } c; c.u = v << 16; return c.f; }
__device__ __forceinline__ float bf_hi(uint v) { union { uint u; float f; } c; c.u = v & 0xffff0000u; return c.f; }

__device__ __forceinline__ void addv8(float* acc, uint4 v) {
  acc[0] += bf_lo(v.x); acc[1] += bf_hi(v.x);
  acc[2] += bf_lo(v.y); acc[3] += bf_hi(v.y);
  acc[4] += bf_lo(v.z); acc[5] += bf_hi(v.z);
  acc[6] += bf_lo(v.w); acc[7] += bf_hi(v.w);
}

// convert 8 consecutive f32 to a bf16x8 fragment (RNE, matches f2bf path)
__device__ __forceinline__ bf16x8 f32_to_bf16x8(const float* p) {
  float4 a = *(const float4*)p;
  float4 b = *(const float4*)(p + 4);
  union { ushort u[8]; bf16x8 v; } r;
  r.u[0] = f2bf(a.x); r.u[1] = f2bf(a.y); r.u[2] = f2bf(a.z); r.u[3] = f2bf(a.w);
  r.u[4] = f2bf(b.x); r.u[5] = f2bf(b.y); r.u[6] = f2bf(b.z); r.u[7] = f2bf(b.w);
  return r.v;
}

// ---------------- merged prep + bucket histogram ----------------
// hist blocks count dst buckets; prep blocks transpose W1/W2/W3 to bf16 and
// zero the dummy rows of yb/zb. (x is consumed as f32 directly by gemm_y.)
__global__ void prep_hist_kernel(const int* __restrict__ dst, int* __restrict__ histG,
                                 int E, int nbuck, int nblocks,
                                 const float* __restrict__ W1, ushort* __restrict__ Wt1,
                                 const float* __restrict__ W2, ushort* __restrict__ Wt2,
                                 const float* __restrict__ W3, ushort* __restrict__ W3t,
                                 ushort* __restrict__ zbN, ushort* __restrict__ ybN) {
  __shared__ int lh[512];
  int tid = threadIdx.x;
  if ((int)blockIdx.x < nblocks) {
    int blk = blockIdx.x;
    for (int i = tid; i < nbuck; i += 256) lh[i] = 0;
    __syncthreads();
    int base = blk * EPB + tid * 4;
#pragma unroll
    for (int it = 0; it < EPB / 1024; ++it) {
      int e = base + it * 1024;
      if (e + 3 < E) {
        int4 d4 = *(const int4*)(dst + e);
        atomicAdd(&lh[d4.x >> 8], 1);
        atomicAdd(&lh[d4.y >> 8], 1);
        atomicAdd(&lh[d4.z >> 8], 1);
        atomicAdd(&lh[d4.w >> 8], 1);
      } else {
#pragma unroll
        for (int q = 0; q < 4; ++q) {
          int ee = e + q;
          if (ee < E) atomicAdd(&lh[dst[ee] >> 8], 1);
        }
      }
    }
    __syncthreads();
    for (int i = tid; i < nbuck; i += 256) histG[(size_t)i * nblocks + blk] = lh[i];
    return;
  }
  int j = ((int)blockIdx.x - nblocks) * 256 + tid;
  if (j < DF * DF) {
    int nr = j >> 7, k = j & 127;
    Wt1[j] = f2bf(W1[(size_t)k * DF + nr]);
    return;
  }
  j -= DF * DF;
  if (j < DF * DF) {
    int nr = j >> 7, k = j & 127;
    Wt2[j] = f2bf(W2[(size_t)k * DF + nr]);
    return;
  }
  j -= DF * DF;
  if (j < 16 * DF) {
    int nr = j >> 7, k = j & 127;
    W3t[j] = (nr < 10) ? f2bf(W3[(size_t)k * 10 + nr]) : (ushort)0;
    return;
  }
  j -= 16 * DF;
  if (j < 16) { ((uint4*)zbN)[j] = (uint4){0, 0, 0, 0}; return; }
  j -= 16;
  if (j < 16) { ((uint4*)ybN)[j] = (uint4){0, 0, 0, 0}; }
}

// ---------------- scan over per-(bucket,block) histogram ----------------
__global__ void scan1_kernel(const int* __restrict__ cnt, int* __restrict__ excl,
                             int* __restrict__ bsums, int n) {
  __shared__ int wsum[4];
  int t = threadIdx.x;
  int base = blockIdx.x * 1024 + t * 4;
  int v[4]; int s = 0;
#pragma unroll
  for (int i = 0; i < 4; i++) { int d = (base + i < n) ? cnt[base + i] : 0; v[i] = s; s += d; }
  int lane = t & 63, w = t >> 6;
  int sc = s;
#pragma unroll
  for (int off = 1; off < 64; off <<= 1) { int o = __shfl_up(sc, off); if (lane >= off) sc += o; }
  if (lane == 63) wsum[w] = sc;
  __syncthreads();
  int woff = 0;
  for (int i = 0; i < w; i++) woff += wsum[i];
  int toff = woff + (sc - s);
#pragma unroll
  for (int i = 0; i < 4; i++) if (base + i < n) excl[base + i] = toff + v[i];
  if (t == 255) bsums[blockIdx.x] = woff + sc;
}

// local exclusive scan of bsums[0..nb) into sbs (nb <= 512), 256 threads
__device__ __forceinline__ void scan_bsums_lds(const int* __restrict__ bsums, int nb,
                                               int* sbs, int* wsum) {
  int t = threadIdx.x;
  int v0 = (2 * t < nb) ? bsums[2 * t] : 0;
  int v1 = (2 * t + 1 < nb) ? bsums[2 * t + 1] : 0;
  int s = v0 + v1;
  int lane = t & 63, w = t >> 6;
  int sc = s;
#pragma unroll
  for (int off = 1; off < 64; off <<= 1) { int o = __shfl_up(sc, off); if (lane >= off) sc += o; }
  if (lane == 63) wsum[w] = sc;
  __syncthreads();
  int woff = 0;
  for (int i = 0; i < w; i++) woff += wsum[i];
  int excl = woff + sc - s;
  sbs[2 * t] = excl;
  sbs[2 * t + 1] = excl + v0;
  __syncthreads();
}

// ---------------- role-split: bucket_scatter || gemm_y = f32(x) @ W1 ----------------
__global__ __launch_bounds__(256) void scatter_gemm_kernel(
    const int* __restrict__ src, const int* __restrict__ dst,
    const int* __restrict__ histE, const int* __restrict__ bsums, int nb,
    uint* __restrict__ eb, int E, int nbuck, int nblocks,
    const float* __restrict__ x, const ushort* __restrict__ Wt1,
    ushort* __restrict__ yb, int n, int ntiles) {
  __shared__ __align__(16) ushort Ws[128 * AST];   // gemm role; scatter overlays cursors here
  int tid = threadIdx.x;
  if ((int)blockIdx.x < nblocks) {
    int* lc   = (int*)Ws;         // 512 ints
    int* sbs  = lc + 512;         // 512 ints
    int* wsum = sbs + 512;        // 4 ints
    int blk = blockIdx.x;
    scan_bsums_lds(bsums, nb, sbs, wsum);
    for (int i = tid; i < nbuck; i += 256) {
      int idx = i * nblocks + blk;
      lc[i] = histE[idx] + sbs[idx >> 10];
    }
    __syncthreads();
    int base = blk * EPB + tid * 4;
#pragma unroll
    for (int it = 0; it < EPB / 1024; ++it) {
      int e = base + it * 1024;
      if (e + 3 < E) {
        int4 s4 = *(const int4*)(src + e);
        int4 d4 = *(const int4*)(dst + e);
        int p0 = atomicAdd(&lc[d4.x >> 8], 1);
        eb[p0] = (uint)s4.x | ((uint)(d4.x & 255) << 24);
        int p1 = atomicAdd(&lc[d4.y >> 8], 1);
        eb[p1] = (uint)s4.y | ((uint)(d4.y & 255) << 24);
        int p2 = atomicAdd(&lc[d4.z >> 8], 1);
        eb[p2] = (uint)s4.z | ((uint)(d4.z & 255) << 24);
        int p3 = atomicAdd(&lc[d4.w >> 8], 1);
        eb[p3] = (uint)s4.w | ((uint)(d4.w & 255) << 24);
      } else {
#pragma unroll
        for (int q = 0; q < 4; ++q) {
          int ee = e + q;
          if (ee < E) {
            int d = dst[ee];
            int pos = atomicAdd(&lc[d >> 8], 1);
            eb[pos] = (uint)src[ee] | ((uint)(d & 255) << 24);
          }
        }
      }
    }
    return;
  }
  // gemm role: yb = bf16(x) @ W1, A read as f32 with in-register convert
  for (int i = tid; i < 128 * 16; i += 256) {
    int r = i >> 4, c = i & 15;
    uint4 v = ((const uint4*)(Wt1 + r * DF))[c];
    *(uint4*)&Ws[r * AST + c * 8] = v;
  }
  __syncthreads();

  int lane = tid & 63, w = tid >> 6;
  int wr = (w >> 1) * 32, wc = (w & 1) * 64;
  int r16 = lane & 15, g8 = (lane >> 4) * 8;
  for (int tile = (int)blockIdx.x - nblocks; tile < ntiles; tile += (int)gridDim.x - nblocks) {
    int node0 = tile * 64;
    int ra = node0 + wr + r16;      if (ra >= n) ra = n - 1;
    int rb = node0 + wr + 16 + r16; if (rb >= n) rb = n - 1;
    const float* pa = x + (size_t)ra * DF + g8;
    const float* pb = x + (size_t)rb * DF + g8;

    f32x4 acc[2][4];
#pragma unroll
    for (int i = 0; i < 2; i++)
#pragma unroll
      for (int j = 0; j < 4; j++) acc[i][j] = (f32x4){0.f, 0.f, 0.f, 0.f};

#pragma unroll
    for (int ks = 0; ks < 4; ++ks) {
      bf16x8 a0 = f32_to_bf16x8(pa + ks * 32);
      bf16x8 a1 = f32_to_bf16x8(pb + ks * 32);
      int k0 = ks * 32 + g8;
#pragma unroll
      for (int j = 0; j < 4; j++) {
        bf16x8 b = *(const bf16x8*)&Ws[(wc + j * 16 + r16) * AST + k0];
        acc[0][j] = __builtin_amdgcn_mfma_f32_16x16x32_bf16(a0, b, acc[0][j], 0, 0, 0);
        acc[1][j] = __builtin_amdgcn_mfma_f32_16x16x32_bf16(a1, b, acc[1][j], 0, 0, 0);
      }
    }

#pragma unroll
    for (int mi = 0; mi < 2; mi++) {
#pragma unroll
      for (int j = 0; j < 4; j++) {
        int col = wc + j * 16 + r16;
        int rowb = wr + mi * 16 + (lane >> 4) * 4;
#pragma unroll
        for (int q = 0; q < 4; q++) {
          int node = node0 + rowb + q;
          if (node < n) yb[(size_t)node * DF + col] = f2bf(acc[mi][j][q]);
        }
      }
    }
  }
}

// ---------------- one block per bucket: counting sort, emit rowptr + csr ----------------
__global__ void bucket_sort_kernel(const uint* __restrict__ eb,
                                   const int* __restrict__ histE, const int* __restrict__ bsums,
                                   int nb, int* __restrict__ rowptr, int* __restrict__ csr,
                                   int N, int E, int nbuck, int nblocks) {
  __shared__ int cnt[256];
  __shared__ int cursor[256];
  __shared__ int sbs[512];
  __shared__ int wsum[4];
  int tid = threadIdx.x, b = blockIdx.x;
  scan_bsums_lds(bsums, nb, sbs, wsum);
  int idx = b * nblocks;
  int beg = histE[idx] + sbs[idx >> 10];
  int end = E;
  if (b + 1 < nbuck) { int i2 = (b + 1) * nblocks; end = histE[i2] + sbs[i2 >> 10]; }
  cnt[tid] = 0;
  __syncthreads();
  for (int e = beg + tid; e < end; e += 256)
    atomicAdd(&cnt[eb[e] >> 24], 1);
  __syncthreads();
  int v = cnt[tid];
  int lane = tid & 63, w = tid >> 6;
  int sc = v;
#pragma unroll
  for (int off = 1; off < 64; off <<= 1) { int o = __shfl_up(sc, off); if (lane >= off) sc += o; }
  if (lane == 63) wsum[w] = sc;
  __syncthreads();
  int woff = 0;
  for (int i = 0; i < w; i++) woff += wsum[i];
  int excl = woff + sc - v;
  int node = (b << 8) + tid;
  if (node <= N) rowptr[node] = beg + excl;
  cursor[tid] = beg + excl;
  __syncthreads();
  for (int e = beg + tid; e < end; e += 256) {
    uint vv = eb[e];
    int pos = atomicAdd(&cursor[vv >> 24], 1);
    csr[pos] = (int)(vv & 0x00FFFFFFu);
  }
}

// ---------------- gather-mean core: acc[8] per 16-lane group ----------------
__device__ __forceinline__ void gather_mean(const ushort* __restrict__ src,
                                            const int* __restrict__ rowptr,
                                            const int* __restrict__ csr,
                                            int node, int n, uint c16, float* acc) {
  int beg = rowptr[node], end = rowptr[node + 1];
  const char* xbase = (const char*)src;
#pragma unroll
  for (int i = 0; i < 8; i++) acc[i] = 0.f;
  int deg = end - beg;
  if (deg > 0) {
#pragma unroll 1
    for (int e = beg; e < end; e += 4) {
      int e1 = e + 1, e2 = e + 2, e3 = e + 3;
      uint r0 = (uint)csr[e];
      uint r1 = (e1 < end) ? (uint)csr[e1] : (uint)n;
      uint r2 = (e2 < end) ? (uint)csr[e2] : (uint)n;
      uint r3 = (e3 < end) ? (uint)csr[e3] : (uint)n;
      uint4 v0 = *(const uint4*)(xbase + (r0 * 256u + c16));
      uint4 v1 = *(const uint4*)(xbase + (r1 * 256u + c16));
      uint4 v2 = *(const uint4*)(xbase + (r2 * 256u + c16));
      uint4 v3 = *(const uint4*)(xbase + (r3 * 256u + c16));
      addv8(acc, v0);
      addv8(acc, v1);
      addv8(acc, v2);
      addv8(acc, v3);
    }
    float inv = 1.0f / (float)deg;
#pragma unroll
    for (int i = 0; i < 8; i++) acc[i] *= inv;
  } else {
    uint4 v = *(const uint4*)(xbase + ((uint)node * 256u + c16));
    float t[8] = {0, 0, 0, 0, 0, 0, 0, 0};
    addv8(t, v);
#pragma unroll
    for (int i = 0; i < 8; i++) acc[i] = t[i];
  }
}

// ---------------- agg1 + fused GEMM2: zb = tanh(mean_or_self(yb)+b1) @ W2 ----------
// Block = 16 nodes. Groups gather+tanh into Hs (bf16); then all 4 waves MFMA
// Hs @ Wt2 (B-frags from global, L1-resident); Z restaged in Hs; coalesced store.
__global__ __launch_bounds__(256) void agg1_gemm_kernel(
    const ushort* __restrict__ yb, const int* __restrict__ rowptr,
    const int* __restrict__ csr, const float* __restrict__ b1,
    const ushort* __restrict__ Wt2, ushort* __restrict__ zb, int n) {
  __shared__ __align__(16) ushort Hs[16 * AST];
  int tid = threadIdx.x;
  int node = (blockIdx.x * 256 + tid) >> 4;
  int node_ib = tid >> 4;
  uint c16 = (uint)(tid & 15) * 16u;
  uint4 hr = (uint4){0, 0, 0, 0};
  if (node < n) {
    float acc[8];
    gather_mean(yb, rowptr, csr, node, n, c16, acc);
    int d8 = (tid & 15) * 8;
    float4 bA = *(const float4*)(b1 + d8);
    float4 bB = *(const float4*)(b1 + d8 + 4);
    float h0 = tanhf(acc[0] + bA.x), h1 = tanhf(acc[1] + bA.y);
    float h2 = tanhf(acc[2] + bA.z), h3 = tanhf(acc[3] + bA.w);
    float h4 = tanhf(acc[4] + bB.x), h5 = tanhf(acc[5] + bB.y);
    float h6 = tanhf(acc[6] + bB.z), h7 = tanhf(acc[7] + bB.w);
    hr.x = (uint)f2bf(h0) | ((uint)f2bf(h1) << 16);
    hr.y = (uint)f2bf(h2) | ((uint)f2bf(h3) << 16);
    hr.z = (uint)f2bf(h4) | ((uint)f2bf(h5) << 16);
    hr.w = (uint)f2bf(h6) | ((uint)f2bf(h7) << 16);
  }
  *(uint4*)&Hs[node_ib * AST + (tid & 15) * 8] = hr;
  __syncthreads();

  // GEMM: Z[16][128] = Hs @ Wt2^T. Wave w -> cols [w*32, w*32+32).
  int lane = tid & 63, w = tid >> 6;
  int r16 = lane & 15, g8 = (lane >> 4) * 8;
  int wc = w * 32;
  f32x4 zacc[2];
  zacc[0] = (f32x4){0.f, 0.f, 0.f, 0.f};
  zacc[1] = (f32x4){0.f, 0.f, 0.f, 0.f};
#pragma unroll
  for (int ks = 0; ks < 4; ++ks) {
    bf16x8 a = *(const bf16x8*)&Hs[r16 * AST + ks * 32 + g8];
    int k0 = ks * 32 + g8;
#pragma unroll
    for (int j = 0; j < 2; ++j) {
      bf16x8 b = *(const bf16x8*)&Wt2[(size_t)(wc + j * 16 + r16) * DF + k0];
      zacc[j] = __builtin_amdgcn_mfma_f32_16x16x32_bf16(a, b, zacc[j], 0, 0, 0);
    }
  }
  __syncthreads();   // A-frag reads of Hs done; overwrite with Z

#pragma unroll
  for (int j = 0; j < 2; ++j) {
    int col = wc + j * 16 + r16;
#pragma unroll
    for (int q = 0; q < 4; ++q) {
      int row = (lane >> 4) * 4 + q;
      Hs[row * AST + col] = f2bf(zacc[j][q]);
    }
  }
  __syncthreads();

  if (node < n) {
    uint4 zv = *(const uint4*)&Hs[node_ib * AST + (tid & 15) * 8];
    *(uint4*)((char*)zb + ((uint)node * 256u + c16)) = zv;
  }
}

// ---------------- agg2 + MFMA head: logits = tanh(mean_or_self(zb)+b2) @ W3 + b3 ----------
__global__ __launch_bounds__(256) void agg_head_kernel(
    const ushort* __restrict__ zb, const int* __restrict__ rowptr,
    const int* __restrict__ csr, const float* __restrict__ b2,
    const ushort* __restrict__ W3t, const float* __restrict__ b3,
    float* __restrict__ out, int n) {
  __shared__ __align__(16) ushort Hs[16 * AST];
  __shared__ __align__(16) ushort W3s[16 * AST];
  int tid = threadIdx.x;
  {
    int r = tid >> 4, c = tid & 15;
    uint4 v = ((const uint4*)(W3t + r * DF))[c];
    *(uint4*)&W3s[r * AST + c * 8] = v;
  }
  int node = (blockIdx.x * 256 + tid) >> 4;
  int node_ib = tid >> 4;
  uint c16 = (uint)(tid & 15) * 16u;
  uint4 hr = (uint4){0, 0, 0, 0};
  if (node < n) {
    float acc[8];
    gather_mean(zb, rowptr, csr, node, n, c16, acc);
    int d8 = (tid & 15) * 8;
    float4 bA = *(const float4*)(b2 + d8);
    float4 bB = *(const float4*)(b2 + d8 + 4);
    float h0 = tanhf(acc[0] + bA.x), h1 = tanhf(acc[1] + bA.y);
    float h2 = tanhf(acc[2] + bA.z), h3 = tanhf(acc[3] + bA.w);
    float h4 = tanhf(acc[4] + bB.x), h5 = tanhf(acc[5] + bB.y);
    float h6 = tanhf(acc[6] + bB.z), h7 = tanhf(acc[7] + bB.w);
    hr.x = (uint)f2bf(h0) | ((uint)f2bf(h1) << 16);
    hr.y = (uint)f2bf(h2) | ((uint)f2bf(h3) << 16);
    hr.z = (uint)f2bf(h4) | ((uint)f2bf(h5) << 16);
    hr.w = (uint)f2bf(h6) | ((uint)f2bf(h7) << 16);
  }
  *(uint4*)&Hs[node_ib * AST + (tid & 15) * 8] = hr;
  __syncthreads();

  if (tid < 64) {
    int l16 = tid & 15, g8 = (tid >> 4) * 8;
    f32x4 acc = (f32x4){0.f, 0.f, 0.f, 0.f};
#pragma unroll
    for (int ks = 0; ks < 4; ++ks) {
      bf16x8 a = *(const bf16x8*)&Hs[l16 * AST + ks * 32 + g8];
      bf16x8 b = *(const bf16x8*)&W3s[l16 * AST + ks * 32 + g8];
      acc = __builtin_amdgcn_mfma_f32_16x16x32_bf16(a, b, acc, 0, 0, 0);
    }
    if (l16 < 10) {
      float bv = b3[l16];
#pragma unroll
      for (int q = 0; q < 4; ++q) {
        int nib = (tid >> 4) * 4 + q;
        int nd = blockIdx.x * 16 + nib;
        if (nd < n) out[(size_t)nd * 10 + l16] = acc[q] + bv;
      }
    }
  }
}

extern "C" void kernel_launch(void* const* d_in, const int* in_sizes, int n_in,
                              void* d_out, int out_size, void* d_ws, size_t ws_size,
                              hipStream_t stream) {
  const float* x    = (const float*)d_in[0];
  const int*   esrc = (const int*)d_in[1];
  const int*   edst = (const int*)d_in[2];
  const float* W1   = (const float*)d_in[3];
  const float* b1   = (const float*)d_in[4];
  const float* W2   = (const float*)d_in[5];
  const float* b2   = (const float*)d_in[6];
  const float* W3   = (const float*)d_in[7];
  const float* b3   = (const float*)d_in[8];
  float* out = (float*)d_out;

  const int N = in_sizes[0] / DF;   // 100000
  const int E = in_sizes[1];        // 1600000

  const int nbuck   = (N + 255) >> 8;            // 391
  const int nblocks = (E + EPB - 1) / EPB;       // 391
  const int M = nbuck * nblocks;                 // ~153K

  // workspace layout
  char* ws = (char*)d_ws;
  int*  rowptr = (int*)ws;               // N+1
  int*  csr    = rowptr + (N + 1);       // E
  int*  histG  = csr + E;                // M
  int*  histE  = histG + M;              // M
  int*  bsums2 = histE + M;              // 1024
  uint* eb     = (uint*)(bsums2 + 1024); // E
  size_t off = (size_t)((char*)(eb + E) - ws);
  off = (off + 255) & ~(size_t)255;
  ushort* Wt1 = (ushort*)(ws + off);     off += (size_t)DF * DF * 2;
  ushort* Wt2 = (ushort*)(ws + off);     off += (size_t)DF * DF * 2;
  ushort* W3t = (ushort*)(ws + off);     off += (size_t)16 * DF * 2; off = (off + 255) & ~(size_t)255;
  ushort* yb  = (ushort*)(ws + off);     off += (size_t)(N + 1) * DF * 2; off = (off + 255) & ~(size_t)255;
  ushort* zb  = (ushort*)(ws + off);     // N+1 rows (zero row N)

  // merged prep + hist
  int prep_total = 2 * DF * DF + 16 * DF + 32;
  int prep_blocks = (prep_total + 255) / 256;
  prep_hist_kernel<<<nblocks + prep_blocks, 256, 0, stream>>>(
      edst, histG, E, nbuck, nblocks,
      W1, Wt1, W2, Wt2, W3, W3t,
      zb + (size_t)N * DF, yb + (size_t)N * DF);

  int nb_m = (M + 1023) / 1024;
  int ntiles = (N + 63) / 64;

  scan1_kernel<<<nb_m, 256, 0, stream>>>(histG, histE, bsums2, M);

  // bucket_scatter || gemm_y = f32(x) @ W1
  scatter_gemm_kernel<<<nblocks + 512, 256, 0, stream>>>(
      esrc, edst, histE, bsums2, nb_m, eb, E, nbuck, nblocks,
      x, Wt1, yb, N, ntiles);

  bucket_sort_kernel<<<nbuck, 256, 0, stream>>>(eb, histE, bsums2, nb_m, rowptr, csr, N, E, nbuck, nblocks);

  int agg_blocks = (N + 15) / 16;

  // layer 1 + layer 2 GEMM fused: zb = tanh(mean_or_self(yb)+b1) @ W2
  agg1_gemm_kernel<<<agg_blocks, 256, 0, stream>>>(yb, rowptr, csr, b1, Wt2, zb, N);
  // layer 2 aggregate + MFMA head
  agg_head_kernel<<<agg_blocks, 256, 0, stream>>>(zb, rowptr, csr, b2, W3t, b3, out, N);
}